// Round 8
// baseline (898.572 us; speedup 1.0000x reference)
//
#include <hip/hip_runtime.h>
#include <hip/hip_bf16.h>
#include <stdint.h>
#include <stddef.h>

using bf16 = __hip_bfloat16;
typedef __bf16 bf16x8 __attribute__((ext_vector_type(8)));
typedef float f32x4 __attribute__((ext_vector_type(4)));

#define P_  16384

// ---------------------------------------------------------------- async g->LDS
__device__ __forceinline__ void gload16(const void* g, void* l) {
    __builtin_amdgcn_global_load_lds((const __attribute__((address_space(1))) void*)g,
                                     (__attribute__((address_space(3))) void*)l, 16, 0, 0);
}

// ---------------------------------------------------------------- GEMM (B^T)
struct GArgs {
    const bf16* A; const bf16* B; void* C;
    const float* bias;    // column bias
    const float* aux1;    // adj_W (M6)
    int M, N, K, ldc, kchunk;
    // MODE 9 extras / MODE 0 dual (z=1) pointers:
    void* dst1; void* dst2; void* dst3; void* dstH;
    const float* cb0; const float* cb1; const float* cb2; const float* cb3;
    const float* a1gv; const float* Ahp; const float* Aop; const float* b1p;
};

// C[M,N] = A[M,K] @ B^T, B stored N x K row-major, both bf16.
// 128x128 tile, BK=64, XOR-swizzled LDS (slot = g ^ (row&7)), 4 waves 2x2,
// 4x4 frags of 16x16x32 MFMA.  (256,4): measured sweet spot — (256,5) spills
// (r5: VGPR 64->48, scratch traffic 4x'd FETCH+WRITE, W2 200->554us).
// r8: XCD-aware bijective block swizzle, tested as a SINGLE variable this
// time (r5 bundled it with the spill). Pure permutation; all call-site
// grids have nx*ny % 8 == 0.
// MODE 0: store fp32 (+bias/relu); grid.z==1 switches to {dst1,dst2,dst3,cb1}
// MODE 1: store bf16 (+bias/relu)
// MODE 2: split-K (kchunk=64), atomicAdd fp32, grid.z = K/64
// MODE 6: adj: atomicAdd(C[p], sum_c relu(acc+bias[c])*aux1[c])
// MODE 9: merged W2 quad: grp0 -> a2_ah bf16 + Hbuf fused; grp1 -> a2_o2s;
//         grp2 -> a2_s2o; grp3 -> H_ahg fused (a1g)
template<int MODE, bool RELU, bool BIAS>
__global__ __launch_bounds__(256, 4)
void gemm_bt(GArgs g)
{
    __shared__ __align__(16) bf16 As[128 * 64];
    __shared__ __align__(16) bf16 Bs[128 * 64];

    const int tid  = threadIdx.x;
    const int wave = tid >> 6;
    const int lane = tid & 63;

    // XCD-aware bijective swizzle: contiguous grid chunk per XCD so blocks
    // sharing an A/B panel run temporally adjacent on one XCD's L2.
    const int nx  = gridDim.x;
    const int nwg = nx * gridDim.y;
    int lin = blockIdx.y * nx + blockIdx.x;
    if ((nwg & 7) == 0) lin = (lin & 7) * (nwg >> 3) + (lin >> 3);
    const int tileM = (lin % nx) * 128;
    const int tileN = (lin / nx) * 128;

    const int wr = (wave >> 1) << 6;
    const int wc = (wave & 1) << 6;
    const int M = g.M, N = g.N, K = g.K;

    const bf16* Ap = g.A; const bf16* Bp = g.B;
    void* Cp = g.C; const float* biasp = g.bias;
    if (MODE == 0 && blockIdx.z == 1) {
        Ap = (const bf16*)g.dst1; Bp = (const bf16*)g.dst2;
        Cp = g.dst3; biasp = g.cb1;
    }

    f32x4 acc[4][4] = {};

    // staging: chunk c = wave*256 + j*64 + lane; row = c>>3; slot = c&7;
    // slot holds k-group g = slot ^ (row&7). For this thread:
    //   row&7 = lane>>3, slot = lane&7  ->  g = (lane&7)^(lane>>3)
    const int gk = (((lane & 7) ^ (lane >> 3)) << 3);   // k elem offset 0..56
    int arow[4], brow[4];
    #pragma unroll
    for (int j = 0; j < 4; ++j) {
        int r = wave * 32 + j * 8 + (lane >> 3);
        int gr = tileM + r; if (gr > M - 1) gr = M - 1; arow[j] = gr;
        int gn = tileN + r; if (gn > N - 1) gn = N - 1; brow[j] = gn;
    }
    const int m0 = wr + (lane & 15);
    const int n0 = wc + (lane & 15);
    const int q  = lane >> 4;

    int kbeg = 0, kend = K;
    if constexpr (MODE == 2) { kbeg = blockIdx.z * 64; kend = kbeg + 64; }

    for (int k0 = kbeg; k0 < kend; k0 += 64) {
        #pragma unroll
        for (int j = 0; j < 4; ++j) {
            int c = wave * 256 + j * 64 + lane;
            gload16(Ap + (size_t)arow[j] * K + k0 + gk, (void*)(As + c * 8));
            gload16(Bp + (size_t)brow[j] * K + k0 + gk, (void*)(Bs + c * 8));
        }
        __syncthreads();
        #pragma unroll
        for (int kk = 0; kk < 2; ++kk) {
            // fragment k-group g = kk*4 + q; LDS slot = g ^ (row&7); row&7 = lane&7
            const int gs = ((kk << 2) + q) ^ (lane & 7);
            bf16x8 af[4], bfv[4];
            #pragma unroll
            for (int i = 0; i < 4; ++i) {
                af[i]  = *(const bf16x8*)(As + (m0 + i * 16) * 64 + gs * 8);
                bfv[i] = *(const bf16x8*)(Bs + (n0 + i * 16) * 64 + gs * 8);
            }
            #pragma unroll
            for (int i = 0; i < 4; ++i)
                #pragma unroll
                for (int j = 0; j < 4; ++j)
                    acc[i][j] = __builtin_amdgcn_mfma_f32_16x16x32_bf16(af[i], bfv[j], acc[i][j], 0, 0, 0);
        }
        __syncthreads();
    }

    const int rbase = tileM + wr + ((lane >> 4) << 2);
    const int cbase = tileN + wc + (lane & 15);

    if constexpr (MODE == 0 || MODE == 1) {
        #pragma unroll
        for (int i = 0; i < 4; ++i)
            #pragma unroll
            for (int j = 0; j < 4; ++j)
                #pragma unroll
                for (int r = 0; r < 4; ++r) {
                    int grow = rbase + i * 16 + r;
                    if (grow >= M) continue;
                    int gcol = cbase + j * 16;
                    float v = acc[i][j][r];
                    if (BIAS) v += biasp[gcol];
                    if (RELU) v = fmaxf(v, 0.f);
                    if (MODE == 1) ((bf16*)Cp)[(size_t)grow * g.ldc + gcol] = __float2bfloat16(v);
                    else           ((float*)Cp)[(size_t)grow * g.ldc + gcol] = v;
                }
    } else if constexpr (MODE == 2) {
        #pragma unroll
        for (int i = 0; i < 4; ++i)
            #pragma unroll
            for (int j = 0; j < 4; ++j)
                #pragma unroll
                for (int r = 0; r < 4; ++r) {
                    int grow = rbase + i * 16 + r;
                    if (grow >= M) continue;
                    atomicAdd((float*)Cp + (size_t)grow * g.ldc + cbase + j * 16, acc[i][j][r]);
                }
    } else if constexpr (MODE == 6) {
        #pragma unroll
        for (int i = 0; i < 4; ++i)
            #pragma unroll
            for (int r = 0; r < 4; ++r) {
                float s = 0.f;
                #pragma unroll
                for (int j = 0; j < 4; ++j) {
                    int gcol = cbase + j * 16;
                    s += fmaxf(acc[i][j][r] + biasp[gcol], 0.f) * g.aux1[gcol];
                }
                s += __shfl_xor(s, 1); s += __shfl_xor(s, 2);
                s += __shfl_xor(s, 4); s += __shfl_xor(s, 8);
                if ((lane & 15) == 0)
                    atomicAdd((float*)Cp + rbase + i * 16 + r, s);
            }
    } else if constexpr (MODE == 9) {
        int grp = tileN >> 10;
        int lcb = (tileN & 1023) + wc + (lane & 15);
        #pragma unroll
        for (int i = 0; i < 4; ++i)
            #pragma unroll
            for (int j = 0; j < 4; ++j)
                #pragma unroll
                for (int r = 0; r < 4; ++r) {
                    int p    = rbase + i * 16 + r;
                    int lcol = lcb + j * 16;
                    float accv = acc[i][j][r];
                    if (grp == 0) {
                        bf16 a2b = __float2bfloat16(accv + g.cb0[lcol]);
                        ((bf16*)Cp)[(size_t)p * 1024 + lcol] = a2b;
                        float a1 = g.Ahp[((size_t)(p >> 8)) * 3072 + lcol]
                                 + g.Aop[((size_t)(p & 255)) * 3072 + lcol] + g.b1p[lcol];
                        ((bf16*)g.dstH)[(size_t)p * 1024 + lcol] =
                            __float2bfloat16(fmaxf(a1 * (float)a2b, 0.f));
                    } else if (grp == 1) {
                        ((bf16*)g.dst1)[(size_t)p * 1024 + lcol] =
                            __float2bfloat16(accv + g.cb1[lcol]);
                    } else if (grp == 2) {
                        ((bf16*)g.dst2)[(size_t)p * 1024 + lcol] =
                            __float2bfloat16(accv + g.cb2[lcol]);
                    } else {
                        float a2v = accv + g.cb3[lcol];
                        ((bf16*)g.dst3)[(size_t)p * 1024 + lcol] =
                            __float2bfloat16(fmaxf(g.a1gv[lcol] * a2v, 0.f));
                    }
                }
    }
}

static GArgs mkargs(const bf16* A, const bf16* B, void* C, const float* bias,
                    const float* aux1, int M, int N, int K, int ldc, int kchunk)
{
    GArgs g{};
    g.A = A; g.B = B; g.C = C; g.bias = bias; g.aux1 = aux1;
    g.M = M; g.N = N; g.K = K; g.ldc = ldc; g.kchunk = kchunk;
    return g;
}

// ---------------------------------------------------------------- reductions over H
// Fused row-softmax (over n) + HredH[h,c] = sum_n sh[h,n] *
//   relu((a1[n,c]+b1[c]) * a2[(h*256+n),c]), a1 ld=3072.
__global__ void reduce_o2s(const bf16* __restrict__ a2, const float* __restrict__ a1,
                           const float* __restrict__ b1, const float* __restrict__ adj,
                           bf16* __restrict__ out)
{
    int h = blockIdx.y, cq = blockIdx.x;
    int tid = threadIdx.x;
    int ng = tid >> 5, ct = tid & 31;
    int c = cq * 256 + ct * 8;

    __shared__ float sm[256];
    __shared__ float r1[256];
    {
        float v = adj[h * 256 + tid];
        r1[tid] = v; __syncthreads();
        for (int s = 128; s > 0; s >>= 1) { if (tid < s) r1[tid] = fmaxf(r1[tid], r1[tid + s]); __syncthreads(); }
        float m = r1[0]; __syncthreads();
        float e = expf(v - m);
        r1[tid] = e; __syncthreads();
        for (int s = 128; s > 0; s >>= 1) { if (tid < s) r1[tid] += r1[tid + s]; __syncthreads(); }
        sm[tid] = e / r1[0];
        __syncthreads();
    }

    float b1v[8], accv[8] = {};
    #pragma unroll
    for (int j = 0; j < 8; ++j) b1v[j] = b1[c + j];
    for (int n = ng; n < 256; n += 8) {
        float w = sm[n];
        bf16x8 a2v = *(const bf16x8*)(a2 + ((size_t)(h * 256 + n) << 10) + c);
        const float* a1p = a1 + (size_t)n * 3072 + c;
        #pragma unroll
        for (int j = 0; j < 8; ++j)
            accv[j] += w * fmaxf((a1p[j] + b1v[j]) * (float)a2v[j], 0.f);
    }
    __shared__ float red[8][264];
    #pragma unroll
    for (int j = 0; j < 8; ++j) red[ng][ct * 8 + j] = accv[j];
    __syncthreads();
    for (int s = 4; s > 0; s >>= 1) {
        if (ng < s)
            #pragma unroll
            for (int j = 0; j < 8; ++j) red[ng][ct * 8 + j] += red[ng + s][ct * 8 + j];
        __syncthreads();
    }
    if (ng == 0) {
        bf16x8 o;
        #pragma unroll
        for (int j = 0; j < 8; ++j) o[j] = (__bf16)red[0][ct * 8 + j];
        *(bf16x8*)(out + (size_t)h * 1024 + c) = o;
    }
}

// Fused col-softmax (over h) + HredO[n,c] = sum_h so[n,h] *
//   relu((a1[h,c]+b1[c]) * a2[(h*256+n),c]), a1 ld=2048.
__global__ void reduce_s2o(const bf16* __restrict__ a2, const float* __restrict__ a1,
                           const float* __restrict__ b1, const float* __restrict__ adj,
                           bf16* __restrict__ out)
{
    int n = blockIdx.y, cq = blockIdx.x;
    int tid = threadIdx.x;
    int hg = tid >> 5, ct = tid & 31;
    int c = cq * 256 + ct * 8;

    __shared__ float sm[64];
    if (tid < 64) {
        float v = adj[tid * 256 + n];
        float m = v;
        #pragma unroll
        for (int off = 32; off; off >>= 1) m = fmaxf(m, __shfl_xor(m, off));
        float e = expf(v - m);
        float s = e;
        #pragma unroll
        for (int off = 32; off; off >>= 1) s += __shfl_xor(s, off);
        sm[tid] = e / s;
    }
    __syncthreads();

    float b1v[8], accv[8] = {};
    #pragma unroll
    for (int j = 0; j < 8; ++j) b1v[j] = b1[c + j];
    #pragma unroll
    for (int hh = 0; hh < 8; ++hh) {
        int h = hg + hh * 8;
        float w = sm[h];
        bf16x8 a2v = *(const bf16x8*)(a2 + ((size_t)(h * 256 + n) << 10) + c);
        const float* a1p = a1 + (size_t)h * 2048 + c;
        #pragma unroll
        for (int j = 0; j < 8; ++j)
            accv[j] += w * fmaxf((a1p[j] + b1v[j]) * (float)a2v[j], 0.f);
    }
    __shared__ float red[8][264];
    #pragma unroll
    for (int j = 0; j < 8; ++j) red[hg][ct * 8 + j] = accv[j];
    __syncthreads();
    for (int s = 4; s > 0; s >>= 1) {
        if (hg < s)
            #pragma unroll
            for (int j = 0; j < 8; ++j) red[hg][ct * 8 + j] += red[hg + s][ct * 8 + j];
        __syncthreads();
    }
    if (hg == 0) {
        bf16x8 o;
        #pragma unroll
        for (int j = 0; j < 8; ++j) o[j] = (__bf16)red[0][ct * 8 + j];
        *(bf16x8*)(out + (size_t)n * 1024 + c) = o;
    }
}

// ---------------------------------------------------------------- transposes
__global__ void transp(const float* __restrict__ src, bf16* __restrict__ dst,
                       int rows, int cols, size_t sstride, size_t dstride)
{
    const float* s = src + blockIdx.z * sstride;
    bf16*        d = dst + blockIdx.z * dstride;
    __shared__ float tile[32][33];
    int c0 = blockIdx.x * 32, r0 = blockIdx.y * 32;
    int x = threadIdx.x, y = threadIdx.y;   // (32, 8)
    for (int yy = y; yy < 32; yy += 8) {
        int r = r0 + yy, c = c0 + x;
        tile[yy][x] = (r < rows && c < cols) ? s[(size_t)r * cols + c] : 0.f;
    }
    __syncthreads();
    for (int yy = y; yy < 32; yy += 8) {
        int c = c0 + yy, r = r0 + x;
        if (c < cols && r < rows) d[(size_t)c * rows + r] = __float2bfloat16(tile[x][yy]);
    }
}

struct T9 { const float* s[9]; bf16* d[9]; size_t ss[9]; };
// 9 weights, each 16 z-slices of 1024x64 -> 64x1024; grid (2, 32, 144)
__global__ void transp64b(T9 t)
{
    int pair = blockIdx.z >> 4, slice = blockIdx.z & 15;
    const float* s = t.s[pair] + slice * t.ss[pair];
    bf16*        d = t.d[pair] + slice * 65536;
    __shared__ float tile[32][33];
    int c0 = blockIdx.x * 32, r0 = blockIdx.y * 32;
    int x = threadIdx.x, y = threadIdx.y;
    for (int yy = y; yy < 32; yy += 8)
        tile[yy][x] = s[(size_t)(r0 + yy) * 64 + c0 + x];
    __syncthreads();
    for (int yy = y; yy < 32; yy += 8)
        d[(size_t)(c0 + yy) * 1024 + r0 + x] = __float2bfloat16(tile[x][yy]);
}

struct T4 { const float* s[4]; bf16* d[4]; };
__global__ void transp1024b(T4 t)
{
    const float* s = t.s[blockIdx.z];
    bf16*        d = t.d[blockIdx.z];
    __shared__ float tile[32][33];
    int c0 = blockIdx.x * 32, r0 = blockIdx.y * 32;
    int x = threadIdx.x, y = threadIdx.y;
    for (int yy = y; yy < 32; yy += 8)
        tile[yy][x] = s[(size_t)(r0 + yy) * 1024 + c0 + x];
    __syncthreads();
    for (int yy = y; yy < 32; yy += 8)
        d[(size_t)(c0 + yy) * 1024 + r0 + x] = __float2bfloat16(tile[x][yy]);
}

// ---------------------------------------------------------------- merged prep
// blocks [0,4096): pad_spatial; [4096,5120): cast node_enc; [5120,5152): spW1
// conversion; [5152,5168): sum b3 x4; [5168,5172): a1g (ahg W1 @ gfeat + b1)
struct PrepArgs {
    const float* spatial; bf16* spat_pad;
    const float* node_enc; bf16* enc_bf;
    const float* sp_W1; bf16* spW1t;
    const float* b3s0; const float* b3s1; const float* b3s2; const float* b3s3;
    float* b3d0; float* b3d1; float* b3d2; float* b3d3;
    const float* gf; const float* ahgW1; const float* ahgb1; float* a1g;
};
__global__ void prep_k(PrepArgs a)
{
    int bid = blockIdx.x, tid = threadIdx.x;
    if (bid < 4096) {
        int i = bid * 256 + tid;
        int k = i & 63, p = i >> 6;
        a.spat_pad[i] = __float2bfloat16(k < 36 ? a.spatial[p * 36 + k] : 0.f);
    } else if (bid < 5120) {
        int i = (bid - 4096) * 256 + tid;
        a.enc_bf[i] = __float2bfloat16(a.node_enc[i]);
    } else if (bid < 5152) {
        int i = (bid - 5120) * 256 + tid;
        int k = i & 63, n = i >> 6;
        a.spW1t[i] = __float2bfloat16(k < 36 ? a.sp_W1[k * 128 + n] : 0.f);
    } else if (bid < 5168) {
        int i = (bid - 5152) * 256 + tid;
        int pair = i >> 10, r = i & 1023;
        const float* b3 = (pair == 0) ? a.b3s0 : (pair == 1) ? a.b3s1 : (pair == 2) ? a.b3s2 : a.b3s3;
        float*       bd = (pair == 0) ? a.b3d0 : (pair == 1) ? a.b3d1 : (pair == 2) ? a.b3d2 : a.b3d3;
        float s = 0.f;
        #pragma unroll
        for (int c = 0; c < 16; ++c) s += b3[c * 1024 + r];
        bd[r] = s;
    } else {
        int cs = (bid - 5168) * 256 + tid;
        int c = cs >> 6, s = cs & 63;
        float acc = a.ahgb1[cs];
        for (int gg = 0; gg < 256; ++gg) acc += a.gf[gg] * a.ahgW1[((size_t)c * 256 + gg) * 64 + s];
        a.a1g[cs] = acc;
    }
}

// H = relu((Ah[p>>8] + Ao[p&255] + b1) * a2)
__global__ void hbuild(const float* __restrict__ Ah, int ah_ld,
                       const float* __restrict__ Ao, int ao_ld,
                       const float* __restrict__ b1, const bf16* __restrict__ a2,
                       bf16* __restrict__ H)
{
    size_t base = ((size_t)blockIdx.x * 256 + threadIdx.x) * 8;
    int cs = (int)(base & 1023);
    int p  = (int)(base >> 10);
    const float* ph = Ah + (size_t)(p >> 8) * ah_ld + cs;
    const float* po = Ao + (size_t)(p & 255) * ao_ld + cs;
    bf16x8 av = *(const bf16x8*)(a2 + base);
    bf16x8 o;
    #pragma unroll
    for (int j = 0; j < 8; ++j) {
        float a1 = ph[j] + po[j] + b1[cs + j];
        o[j] = (__bf16)fmaxf(a1 * (float)av[j], 0.f);
    }
    *(bf16x8*)(H + base) = o;
}

// ---------------------------------------------------------------- LN
__global__ void ln_k(const float* __restrict__ x, const float* __restrict__ msgraw,
                     const float* __restrict__ sb3,
                     const float* __restrict__ g, const float* __restrict__ bb,
                     bf16* __restrict__ out)
{
    int row = blockIdx.x, t = threadIdx.x;
    const float* xr = x + (size_t)row * 1024;
    const float* mr = msgraw + (size_t)row * 1024;
    float v[4]; float s = 0.f, ss = 0.f;
    #pragma unroll
    for (int j = 0; j < 4; ++j) {
        int i = t + j * 256;
        v[j] = xr[i] + fmaxf(mr[i] + sb3[i], 0.f);
        s += v[j]; ss += v[j] * v[j];
    }
    __shared__ float r1[256], r2[256];
    r1[t] = s; r2[t] = ss; __syncthreads();
    for (int k = 128; k > 0; k >>= 1) { if (t < k) { r1[t] += r1[t + k]; r2[t] += r2[t + k]; } __syncthreads(); }
    float mean = r1[0] * (1.f / 1024.f);
    float var  = r2[0] * (1.f / 1024.f) - mean * mean;
    float inv  = rsqrtf(var + 1e-5f);
    #pragma unroll
    for (int j = 0; j < 4; ++j) {
        int i = t + j * 256;
        out[(size_t)row * 1024 + i] = __float2bfloat16((v[j] - mean) * inv * g[i] + bb[i]);
    }
}

// ---------------------------------------------------------------- launch
extern "C" void kernel_launch(void* const* d_in, const int* in_sizes, int n_in,
                              void* d_out, int out_size, void* d_ws, size_t ws_size,
                              hipStream_t stream)
{
    const float* node_enc = (const float*)d_in[0];
    const float* spatial  = (const float*)d_in[1];
    const float* gfeat    = (const float*)d_in[2];
    const float* sp_W1 = (const float*)d_in[3];  const float* sp_b1 = (const float*)d_in[4];
    const float* sp_W2 = (const float*)d_in[5];  const float* sp_b2 = (const float*)d_in[6];
    const float* sp_W3 = (const float*)d_in[7];  const float* sp_b3 = (const float*)d_in[8];
    const float* ah_W1 = (const float*)d_in[9];  const float* ah_b1 = (const float*)d_in[10];
    const float* ah_W2 = (const float*)d_in[11]; const float* ah_b2 = (const float*)d_in[12];
    const float* ah_W3 = (const float*)d_in[13]; const float* ah_b3 = (const float*)d_in[14];
    const float* o2s_W1 = (const float*)d_in[15]; const float* o2s_b1 = (const float*)d_in[16];
    const float* o2s_W2 = (const float*)d_in[17]; const float* o2s_b2 = (const float*)d_in[18];
    const float* o2s_W3 = (const float*)d_in[19]; const float* o2s_b3 = (const float*)d_in[20];
    const float* s2o_W1 = (const float*)d_in[21]; const float* s2o_b1 = (const float*)d_in[22];
    const float* s2o_W2 = (const float*)d_in[23]; const float* s2o_b2 = (const float*)d_in[24];
    const float* s2o_W3 = (const float*)d_in[25]; const float* s2o_b3 = (const float*)d_in[26];
    const float* ahg_W1 = (const float*)d_in[27]; const float* ahg_b1 = (const float*)d_in[28];
    const float* ahg_W2 = (const float*)d_in[29]; const float* ahg_b2 = (const float*)d_in[30];
    const float* ahg_W3 = (const float*)d_in[31]; const float* ahg_b3 = (const float*)d_in[32];
    const float* adj_W = (const float*)d_in[33];
    const float* lnh_g = (const float*)d_in[35]; const float* lnh_b = (const float*)d_in[36];
    const float* lno_g = (const float*)d_in[37]; const float* lno_b = (const float*)d_in[38];

    char* w = (char*)d_ws;
    auto alloc = [&](size_t bytes) { char* p = w; w += (bytes + 255) & ~(size_t)255; return p; };
    bf16*  sp      = (bf16*)alloc((size_t)P_ * 1024 * 2);
    bf16*  a2_ah   = (bf16*)alloc((size_t)P_ * 1024 * 2);
    bf16*  Hbuf    = (bf16*)alloc((size_t)P_ * 1024 * 2);
    bf16*  a2_o2s  = (bf16*)alloc((size_t)P_ * 1024 * 2);
    bf16*  a2_s2o  = (bf16*)alloc((size_t)P_ * 1024 * 2);
    bf16*  H_ahg   = (bf16*)alloc((size_t)P_ * 1024 * 2);
    bf16*  spat_pad= (bf16*)alloc((size_t)P_ * 64 * 2);
    bf16*  spL1    = (bf16*)alloc((size_t)P_ * 128 * 2);
    bf16*  spL2    = (bf16*)alloc((size_t)P_ * 256 * 2);
    bf16*  enc_bf  = (bf16*)alloc(256 * 1024 * 2);
    bf16*  henc_bf = (bf16*)alloc(64 * 1024 * 2);
    bf16*  oenc_bf = (bf16*)alloc(256 * 1024 * 2);
    bf16*  HredH   = (bf16*)alloc(64 * 1024 * 2);
    bf16*  HredO   = (bf16*)alloc(256 * 1024 * 2);
    bf16*  spW1t   = (bf16*)alloc(128 * 64 * 2);
    bf16*  spW2t   = (bf16*)alloc(256 * 128 * 2);
    bf16*  spW3t   = (bf16*)alloc(1024 * 256 * 2);
    bf16*  W2cat   = (bf16*)alloc((size_t)4096 * 1024 * 2); // [ah; o2s; s2o; ahg]
    bf16*  W1cat3  = (bf16*)alloc((size_t)3072 * 1024 * 2); // [ahW1tB; o2sW1t; ahW1tT]
    bf16*  W1catF  = (bf16*)alloc((size_t)2048 * 1024 * 2); // [s2oW1t; ahW1tT]
    bf16*  ahW3t   = (bf16*)alloc(1024 * 1024 * 2);
    bf16*  o2sW3t  = (bf16*)alloc(1024 * 1024 * 2);
    bf16*  s2oW3t  = (bf16*)alloc(1024 * 1024 * 2);
    bf16*  ahgW3t  = (bf16*)alloc(1024 * 1024 * 2);
    // zero-init block (single memset: Aoa1x .. msgo are consecutive allocs)
    float* Aoa1x = (float*)alloc(256 * 3072 * 4);   // cols: Ao | a1o2s | Ah(rows<64)
    float* A1f   = (float*)alloc(64 * 2048 * 4);    // cols: a1s2o | Ah_f
    float* Ao_f  = (float*)alloc(256 * 1024 * 4);
    float* adjv  = (float*)alloc(P_ * 4);
    float* msgh  = (float*)alloc(64 * 1024 * 4);
    float* msgo  = (float*)alloc(256 * 1024 * 4);
    float* a1g   = (float*)alloc(1024 * 4);
    float* sb3_ah  = (float*)alloc(4096);
    float* sb3_o2s = (float*)alloc(4096);
    float* sb3_s2o = (float*)alloc(4096);
    float* sb3_ahg = (float*)alloc(4096);

    hipMemsetAsync(Aoa1x, 0, (size_t)((char*)a1g - (char*)Aoa1x), stream);

    // ---- batched weight conversions
    {
        T9 t;
        t.s[0] = ah_W1;                     t.d[0] = W1cat3 + (size_t)2048 * 1024; t.ss[0] = (size_t)2048 * 64; // ahT
        t.s[1] = ah_W1 + (size_t)1024 * 64; t.d[1] = W1cat3;                       t.ss[1] = (size_t)2048 * 64; // ahB
        t.s[2] = o2s_W1;                    t.d[2] = W1cat3 + (size_t)1024 * 1024; t.ss[2] = 65536;
        t.s[3] = s2o_W1;                    t.d[3] = W1catF;                       t.ss[3] = 65536;
        t.s[4] = ah_W1;                     t.d[4] = W1catF + (size_t)1024 * 1024; t.ss[4] = (size_t)2048 * 64; // ahT copy
        t.s[5] = ah_W2;                     t.d[5] = W2cat;                        t.ss[5] = 65536;
        t.s[6] = o2s_W2;                    t.d[6] = W2cat + (size_t)1024 * 1024;  t.ss[6] = 65536;
        t.s[7] = s2o_W2;                    t.d[7] = W2cat + (size_t)2048 * 1024;  t.ss[7] = 65536;
        t.s[8] = ahg_W2;                    t.d[8] = W2cat + (size_t)3072 * 1024;  t.ss[8] = 65536;
        transp64b<<<dim3(2, 32, 144), dim3(32, 8), 0, stream>>>(t);
    }
    {
        T4 t;
        t.s[0] = ah_W3;  t.d[0] = ahW3t;
        t.s[1] = o2s_W3; t.d[1] = o2sW3t;
        t.s[2] = s2o_W3; t.d[2] = s2oW3t;
        t.s[3] = ahg_W3; t.d[3] = ahgW3t;
        transp1024b<<<dim3(32, 32, 4), dim3(32, 8), 0, stream>>>(t);
    }
    dim3 tb(32, 8);
    transp<<<dim3(8, 4, 1),  tb, 0, stream>>>(sp_W2, spW2t, 128, 256, 0, 0);
    transp<<<dim3(32, 8, 1), tb, 0, stream>>>(sp_W3, spW3t, 256, 1024, 0, 0);
    {
        PrepArgs a;
        a.spatial = spatial; a.spat_pad = spat_pad;
        a.node_enc = node_enc; a.enc_bf = enc_bf;
        a.sp_W1 = sp_W1; a.spW1t = spW1t;
        a.b3s0 = ah_b3; a.b3s1 = o2s_b3; a.b3s2 = s2o_b3; a.b3s3 = ahg_b3;
        a.b3d0 = sb3_ah; a.b3d1 = sb3_o2s; a.b3d2 = sb3_s2o; a.b3d3 = sb3_ahg;
        a.gf = gfeat; a.ahgW1 = ahg_W1; a.ahgb1 = ahg_b1; a.a1g = a1g;
        prep_k<<<5172, 256, 0, stream>>>(a);
    }

    // ---- W1 split-K GEMM: enc @ [ahB | o2s | ahT] -> Aoa1x (256 x 3072)
    gemm_bt<2, false, false><<<dim3(2, 24, 16), 256, 0, stream>>>(
        mkargs(enc_bf, W1cat3, Aoa1x, nullptr, nullptr, 256, 3072, 1024, 3072, 64));

    // ---- sp MLP
    gemm_bt<1, true, true><<<dim3(128, 1), 256, 0, stream>>>(
        mkargs(spat_pad, spW1t, spL1, sp_b1, nullptr, P_, 128, 64, 128, 0));
    gemm_bt<1, true, true><<<dim3(128, 2), 256, 0, stream>>>(
        mkargs(spL1, spW2t, spL2, sp_b2, nullptr, P_, 256, 128, 256, 0));
    gemm_bt<1, true, true><<<dim3(128, 8), 256, 0, stream>>>(
        mkargs(spL2, spW3t, sp, sp_b3, nullptr, P_, 1024, 256, 1024, 0));

    // ---- merged W2 GEMM: N=4096 -> a2_ah+Hbuf | a2_o2s | a2_s2o | H_ahg
    {
        GArgs g = mkargs(sp, W2cat, a2_ah, nullptr, nullptr, P_, 4096, 1024, 1024, 0);
        g.dst1 = a2_o2s; g.dst2 = a2_s2o; g.dst3 = H_ahg; g.dstH = Hbuf;
        g.cb0 = ah_b2; g.cb1 = o2s_b2; g.cb2 = s2o_b2; g.cb3 = ahg_b2;
        g.a1gv = a1g; g.Ahp = Aoa1x + 2048; g.Aop = Aoa1x; g.b1p = ah_b1;
        gemm_bt<9, false, false><<<dim3(128, 32), 256, 0, stream>>>(g);
    }

    // ---- adj (softmaxes are fused into the reduce kernels)
    gemm_bt<6, false, false><<<dim3(128, 8), 256, 0, stream>>>(
        mkargs(Hbuf, ahW3t, adjv, sb3_ah, adj_W, P_, 1024, 1024, 1024, 0));

    // ---- msg_h = Hred_h @ o2sW3 -> h_enc'
    reduce_o2s<<<dim3(4, 64), 256, 0, stream>>>(a2_o2s, Aoa1x + 1024, o2s_b1, adjv, HredH);
    gemm_bt<2, false, false><<<dim3(1, 8, 16), 256, 0, stream>>>(
        mkargs(HredH, o2sW3t, msgh, nullptr, nullptr, 64, 1024, 1024, 1024, 64));
    ln_k<<<64, 256, 0, stream>>>(node_enc, msgh, sb3_o2s, lnh_g, lnh_b, henc_bf);

    // ---- {a1s2o | Ah_f}
    gemm_bt<2, false, false><<<dim3(1, 16, 16), 256, 0, stream>>>(
        mkargs(henc_bf, W1catF, A1f, nullptr, nullptr, 64, 2048, 1024, 2048, 64));

    // ---- msg_o = Hred_o @ s2oW3 -> o_enc'
    reduce_s2o<<<dim3(4, 256), 256, 0, stream>>>(a2_s2o, A1f, s2o_b1, adjv, HredO);
    gemm_bt<2, false, false><<<dim3(2, 8, 16), 256, 0, stream>>>(
        mkargs(HredO, s2oW3t, msgo, nullptr, nullptr, 256, 1024, 1024, 1024, 64));
    ln_k<<<256, 256, 0, stream>>>(node_enc, msgo, sb3_s2o, lno_g, lno_b, oenc_bf);

    // ---- Ao_f, final ah-head H
    gemm_bt<2, false, false><<<dim3(2, 8, 16), 256, 0, stream>>>(
        mkargs(oenc_bf, W1cat3, Ao_f, nullptr, nullptr, 256, 1024, 1024, 1024, 64));
    hbuild<<<8192, 256, 0, stream>>>(A1f + 1024, 2048, Ao_f, 1024, ah_b1, a2_ah, Hbuf);

    // ---- f_local (z=0) + f_glob (z=1) in one dispatch
    {
        GArgs g = mkargs(Hbuf, ahW3t, (float*)d_out, sb3_ah, nullptr, P_, 1024, 1024, 2048, 0);
        g.dst1 = (void*)H_ahg; g.dst2 = (void*)ahgW3t;
        g.dst3 = (void*)((float*)d_out + 1024); g.cb1 = sb3_ahg;
        gemm_bt<0, true, true><<<dim3(128, 8, 2), 256, 0, stream>>>(g);
    }

    (void)in_sizes; (void)n_in; (void)out_size; (void)ws_size;
}

// Round 9
// 775.154 us; speedup vs baseline: 1.1592x; 1.1592x over previous
//
#include <hip/hip_runtime.h>
#include <hip/hip_bf16.h>
#include <stdint.h>
#include <stddef.h>

using bf16 = __hip_bfloat16;
typedef __bf16 bf16x8 __attribute__((ext_vector_type(8)));
typedef float f32x4 __attribute__((ext_vector_type(4)));

#define P_  16384

// ---------------------------------------------------------------- async g->LDS
__device__ __forceinline__ void gload16(const void* g, void* l) {
    __builtin_amdgcn_global_load_lds((const __attribute__((address_space(1))) void*)g,
                                     (__attribute__((address_space(3))) void*)l, 16, 0, 0);
}

// ---------------------------------------------------------------- GEMM (B^T)
struct GArgs {
    const bf16* A; const bf16* B; void* C;
    const float* bias;    // column bias
    const float* aux1;    // adj_W (M6)
    int M, N, K, ldc, kchunk;
    // MODE 9 extras / MODE 0 dual (z=1) pointers:
    void* dst1; void* dst2; void* dst3; void* dstH;
    const float* cb0; const float* cb1; const float* cb2; const float* cb3;
    const float* a1gv; const float* Ahp; const float* Aop; const float* b1p;
};

// C[M,N] = A[M,K] @ B^T, B stored N x K row-major, both bf16.
// 128x128 tile, BK=64, XOR-swizzled LDS (slot = g ^ (row&7)), 4 waves 2x2,
// 4x4 frags of 16x16x32 MFMA.  (256,4): measured sweet spot — (256,5) spills
// (r5: VGPR 64->48, scratch 4x'd FETCH+WRITE, W2 200->554us).
// LINEAR blockIdx mapping is XCD-optimal here (r8 measured): XCD = lin%8 =
// blockIdx.x%8 pins each XCD's 16 A-panels (4MB = L2) across all y-iters;
// the chunked XCD swizzle broke that pinning (FETCH 203->532MB, W2 +50%).
// Do NOT add a block swizzle to this kernel.
// MODE 0: store fp32 (+bias/relu); grid.z==1 switches to {dst1,dst2,dst3,cb1}
// MODE 1: store bf16 (+bias/relu)
// MODE 2: split-K (kchunk=64), atomicAdd fp32, grid.z = K/64
// MODE 6: adj: atomicAdd(C[p], sum_c relu(acc+bias[c])*aux1[c])
// MODE 9: merged W2 quad: grp0 -> a2_ah bf16 + Hbuf fused; grp1 -> a2_o2s;
//         grp2 -> a2_s2o; grp3 -> H_ahg fused (a1g)
template<int MODE, bool RELU, bool BIAS>
__global__ __launch_bounds__(256, 4)
void gemm_bt(GArgs g)
{
    __shared__ __align__(16) bf16 As[128 * 64];
    __shared__ __align__(16) bf16 Bs[128 * 64];

    const int tid  = threadIdx.x;
    const int wave = tid >> 6;
    const int lane = tid & 63;
    const int tileM = blockIdx.x * 128;
    const int tileN = blockIdx.y * 128;
    const int wr = (wave >> 1) << 6;
    const int wc = (wave & 1) << 6;
    const int M = g.M, N = g.N, K = g.K;

    const bf16* Ap = g.A; const bf16* Bp = g.B;
    void* Cp = g.C; const float* biasp = g.bias;
    if (MODE == 0 && blockIdx.z == 1) {
        Ap = (const bf16*)g.dst1; Bp = (const bf16*)g.dst2;
        Cp = g.dst3; biasp = g.cb1;
    }

    f32x4 acc[4][4] = {};

    // staging: chunk c = wave*256 + j*64 + lane; row = c>>3; slot = c&7;
    // slot holds k-group g = slot ^ (row&7). For this thread:
    //   row&7 = lane>>3, slot = lane&7  ->  g = (lane&7)^(lane>>3)
    const int gk = (((lane & 7) ^ (lane >> 3)) << 3);   // k elem offset 0..56
    int arow[4], brow[4];
    #pragma unroll
    for (int j = 0; j < 4; ++j) {
        int r = wave * 32 + j * 8 + (lane >> 3);
        int gr = tileM + r; if (gr > M - 1) gr = M - 1; arow[j] = gr;
        int gn = tileN + r; if (gn > N - 1) gn = N - 1; brow[j] = gn;
    }
    const int m0 = wr + (lane & 15);
    const int n0 = wc + (lane & 15);
    const int q  = lane >> 4;

    int kbeg = 0, kend = K;
    if constexpr (MODE == 2) { kbeg = blockIdx.z * 64; kend = kbeg + 64; }

    for (int k0 = kbeg; k0 < kend; k0 += 64) {
        #pragma unroll
        for (int j = 0; j < 4; ++j) {
            int c = wave * 256 + j * 64 + lane;
            gload16(Ap + (size_t)arow[j] * K + k0 + gk, (void*)(As + c * 8));
            gload16(Bp + (size_t)brow[j] * K + k0 + gk, (void*)(Bs + c * 8));
        }
        __syncthreads();
        #pragma unroll
        for (int kk = 0; kk < 2; ++kk) {
            // fragment k-group g = kk*4 + q; LDS slot = g ^ (row&7); row&7 = lane&7
            const int gs = ((kk << 2) + q) ^ (lane & 7);
            bf16x8 af[4], bfv[4];
            #pragma unroll
            for (int i = 0; i < 4; ++i) {
                af[i]  = *(const bf16x8*)(As + (m0 + i * 16) * 64 + gs * 8);
                bfv[i] = *(const bf16x8*)(Bs + (n0 + i * 16) * 64 + gs * 8);
            }
            #pragma unroll
            for (int i = 0; i < 4; ++i)
                #pragma unroll
                for (int j = 0; j < 4; ++j)
                    acc[i][j] = __builtin_amdgcn_mfma_f32_16x16x32_bf16(af[i], bfv[j], acc[i][j], 0, 0, 0);
        }
        __syncthreads();
    }

    const int rbase = tileM + wr + ((lane >> 4) << 2);
    const int cbase = tileN + wc + (lane & 15);

    if constexpr (MODE == 0 || MODE == 1) {
        #pragma unroll
        for (int i = 0; i < 4; ++i)
            #pragma unroll
            for (int j = 0; j < 4; ++j)
                #pragma unroll
                for (int r = 0; r < 4; ++r) {
                    int grow = rbase + i * 16 + r;
                    if (grow >= M) continue;
                    int gcol = cbase + j * 16;
                    float v = acc[i][j][r];
                    if (BIAS) v += biasp[gcol];
                    if (RELU) v = fmaxf(v, 0.f);
                    if (MODE == 1) ((bf16*)Cp)[(size_t)grow * g.ldc + gcol] = __float2bfloat16(v);
                    else           ((float*)Cp)[(size_t)grow * g.ldc + gcol] = v;
                }
    } else if constexpr (MODE == 2) {
        #pragma unroll
        for (int i = 0; i < 4; ++i)
            #pragma unroll
            for (int j = 0; j < 4; ++j)
                #pragma unroll
                for (int r = 0; r < 4; ++r) {
                    int grow = rbase + i * 16 + r;
                    if (grow >= M) continue;
                    atomicAdd((float*)Cp + (size_t)grow * g.ldc + cbase + j * 16, acc[i][j][r]);
                }
    } else if constexpr (MODE == 6) {
        #pragma unroll
        for (int i = 0; i < 4; ++i)
            #pragma unroll
            for (int r = 0; r < 4; ++r) {
                float s = 0.f;
                #pragma unroll
                for (int j = 0; j < 4; ++j) {
                    int gcol = cbase + j * 16;
                    s += fmaxf(acc[i][j][r] + biasp[gcol], 0.f) * g.aux1[gcol];
                }
                s += __shfl_xor(s, 1); s += __shfl_xor(s, 2);
                s += __shfl_xor(s, 4); s += __shfl_xor(s, 8);
                if ((lane & 15) == 0)
                    atomicAdd((float*)Cp + rbase + i * 16 + r, s);
            }
    } else if constexpr (MODE == 9) {
        int grp = tileN >> 10;
        int lcb = (tileN & 1023) + wc + (lane & 15);
        #pragma unroll
        for (int i = 0; i < 4; ++i)
            #pragma unroll
            for (int j = 0; j < 4; ++j)
                #pragma unroll
                for (int r = 0; r < 4; ++r) {
                    int p    = rbase + i * 16 + r;
                    int lcol = lcb + j * 16;
                    float accv = acc[i][j][r];
                    if (grp == 0) {
                        bf16 a2b = __float2bfloat16(accv + g.cb0[lcol]);
                        ((bf16*)Cp)[(size_t)p * 1024 + lcol] = a2b;
                        float a1 = g.Ahp[((size_t)(p >> 8)) * 3072 + lcol]
                                 + g.Aop[((size_t)(p & 255)) * 3072 + lcol] + g.b1p[lcol];
                        ((bf16*)g.dstH)[(size_t)p * 1024 + lcol] =
                            __float2bfloat16(fmaxf(a1 * (float)a2b, 0.f));
                    } else if (grp == 1) {
                        ((bf16*)g.dst1)[(size_t)p * 1024 + lcol] =
                            __float2bfloat16(accv + g.cb1[lcol]);
                    } else if (grp == 2) {
                        ((bf16*)g.dst2)[(size_t)p * 1024 + lcol] =
                            __float2bfloat16(accv + g.cb2[lcol]);
                    } else {
                        float a2v = accv + g.cb3[lcol];
                        ((bf16*)g.dst3)[(size_t)p * 1024 + lcol] =
                            __float2bfloat16(fmaxf(g.a1gv[lcol] * a2v, 0.f));
                    }
                }
    }
}

static GArgs mkargs(const bf16* A, const bf16* B, void* C, const float* bias,
                    const float* aux1, int M, int N, int K, int ldc, int kchunk)
{
    GArgs g{};
    g.A = A; g.B = B; g.C = C; g.bias = bias; g.aux1 = aux1;
    g.M = M; g.N = N; g.K = K; g.ldc = ldc; g.kchunk = kchunk;
    return g;
}

// ---------------------------------------------------------------- reductions over H
// Fused row-softmax (over n) + HredH[h,c] = sum_n sh[h,n] *
//   relu((a1[n,c]+b1[c]) * a2[(h*256+n),c]), a1 ld=3072.
__global__ void reduce_o2s(const bf16* __restrict__ a2, const float* __restrict__ a1,
                           const float* __restrict__ b1, const float* __restrict__ adj,
                           bf16* __restrict__ out)
{
    int h = blockIdx.y, cq = blockIdx.x;
    int tid = threadIdx.x;
    int ng = tid >> 5, ct = tid & 31;
    int c = cq * 256 + ct * 8;

    __shared__ float sm[256];
    __shared__ float r1[256];
    {
        float v = adj[h * 256 + tid];
        r1[tid] = v; __syncthreads();
        for (int s = 128; s > 0; s >>= 1) { if (tid < s) r1[tid] = fmaxf(r1[tid], r1[tid + s]); __syncthreads(); }
        float m = r1[0]; __syncthreads();
        float e = expf(v - m);
        r1[tid] = e; __syncthreads();
        for (int s = 128; s > 0; s >>= 1) { if (tid < s) r1[tid] += r1[tid + s]; __syncthreads(); }
        sm[tid] = e / r1[0];
        __syncthreads();
    }

    float b1v[8], accv[8] = {};
    #pragma unroll
    for (int j = 0; j < 8; ++j) b1v[j] = b1[c + j];
    for (int n = ng; n < 256; n += 8) {
        float w = sm[n];
        bf16x8 a2v = *(const bf16x8*)(a2 + ((size_t)(h * 256 + n) << 10) + c);
        const float* a1p = a1 + (size_t)n * 3072 + c;
        #pragma unroll
        for (int j = 0; j < 8; ++j)
            accv[j] += w * fmaxf((a1p[j] + b1v[j]) * (float)a2v[j], 0.f);
    }
    __shared__ float red[8][264];
    #pragma unroll
    for (int j = 0; j < 8; ++j) red[ng][ct * 8 + j] = accv[j];
    __syncthreads();
    for (int s = 4; s > 0; s >>= 1) {
        if (ng < s)
            #pragma unroll
            for (int j = 0; j < 8; ++j) red[ng][ct * 8 + j] += red[ng + s][ct * 8 + j];
        __syncthreads();
    }
    if (ng == 0) {
        bf16x8 o;
        #pragma unroll
        for (int j = 0; j < 8; ++j) o[j] = (__bf16)red[0][ct * 8 + j];
        *(bf16x8*)(out + (size_t)h * 1024 + c) = o;
    }
}

// Fused col-softmax (over h) + HredO[n,c] = sum_h so[n,h] *
//   relu((a1[h,c]+b1[c]) * a2[(h*256+n),c]), a1 ld=2048.
__global__ void reduce_s2o(const bf16* __restrict__ a2, const float* __restrict__ a1,
                           const float* __restrict__ b1, const float* __restrict__ adj,
                           bf16* __restrict__ out)
{
    int n = blockIdx.y, cq = blockIdx.x;
    int tid = threadIdx.x;
    int hg = tid >> 5, ct = tid & 31;
    int c = cq * 256 + ct * 8;

    __shared__ float sm[64];
    if (tid < 64) {
        float v = adj[tid * 256 + n];
        float m = v;
        #pragma unroll
        for (int off = 32; off; off >>= 1) m = fmaxf(m, __shfl_xor(m, off));
        float e = expf(v - m);
        float s = e;
        #pragma unroll
        for (int off = 32; off; off >>= 1) s += __shfl_xor(s, off);
        sm[tid] = e / s;
    }
    __syncthreads();

    float b1v[8], accv[8] = {};
    #pragma unroll
    for (int j = 0; j < 8; ++j) b1v[j] = b1[c + j];
    #pragma unroll
    for (int hh = 0; hh < 8; ++hh) {
        int h = hg + hh * 8;
        float w = sm[h];
        bf16x8 a2v = *(const bf16x8*)(a2 + ((size_t)(h * 256 + n) << 10) + c);
        const float* a1p = a1 + (size_t)h * 2048 + c;
        #pragma unroll
        for (int j = 0; j < 8; ++j)
            accv[j] += w * fmaxf((a1p[j] + b1v[j]) * (float)a2v[j], 0.f);
    }
    __shared__ float red[8][264];
    #pragma unroll
    for (int j = 0; j < 8; ++j) red[hg][ct * 8 + j] = accv[j];
    __syncthreads();
    for (int s = 4; s > 0; s >>= 1) {
        if (hg < s)
            #pragma unroll
            for (int j = 0; j < 8; ++j) red[hg][ct * 8 + j] += red[hg + s][ct * 8 + j];
        __syncthreads();
    }
    if (hg == 0) {
        bf16x8 o;
        #pragma unroll
        for (int j = 0; j < 8; ++j) o[j] = (__bf16)red[0][ct * 8 + j];
        *(bf16x8*)(out + (size_t)n * 1024 + c) = o;
    }
}

// ---------------------------------------------------------------- transposes
__global__ void transp(const float* __restrict__ src, bf16* __restrict__ dst,
                       int rows, int cols, size_t sstride, size_t dstride)
{
    const float* s = src + blockIdx.z * sstride;
    bf16*        d = dst + blockIdx.z * dstride;
    __shared__ float tile[32][33];
    int c0 = blockIdx.x * 32, r0 = blockIdx.y * 32;
    int x = threadIdx.x, y = threadIdx.y;   // (32, 8)
    for (int yy = y; yy < 32; yy += 8) {
        int r = r0 + yy, c = c0 + x;
        tile[yy][x] = (r < rows && c < cols) ? s[(size_t)r * cols + c] : 0.f;
    }
    __syncthreads();
    for (int yy = y; yy < 32; yy += 8) {
        int c = c0 + yy, r = r0 + x;
        if (c < cols && r < rows) d[(size_t)c * rows + r] = __float2bfloat16(tile[x][yy]);
    }
}

struct T9 { const float* s[9]; bf16* d[9]; size_t ss[9]; };
// 9 weights, each 16 z-slices of 1024x64 -> 64x1024; grid (2, 32, 144)
__global__ void transp64b(T9 t)
{
    int pair = blockIdx.z >> 4, slice = blockIdx.z & 15;
    const float* s = t.s[pair] + slice * t.ss[pair];
    bf16*        d = t.d[pair] + slice * 65536;
    __shared__ float tile[32][33];
    int c0 = blockIdx.x * 32, r0 = blockIdx.y * 32;
    int x = threadIdx.x, y = threadIdx.y;
    for (int yy = y; yy < 32; yy += 8)
        tile[yy][x] = s[(size_t)(r0 + yy) * 64 + c0 + x];
    __syncthreads();
    for (int yy = y; yy < 32; yy += 8)
        d[(size_t)(c0 + yy) * 1024 + r0 + x] = __float2bfloat16(tile[x][yy]);
}

struct T4 { const float* s[4]; bf16* d[4]; };
__global__ void transp1024b(T4 t)
{
    const float* s = t.s[blockIdx.z];
    bf16*        d = t.d[blockIdx.z];
    __shared__ float tile[32][33];
    int c0 = blockIdx.x * 32, r0 = blockIdx.y * 32;
    int x = threadIdx.x, y = threadIdx.y;
    for (int yy = y; yy < 32; yy += 8)
        tile[yy][x] = s[(size_t)(r0 + yy) * 1024 + c0 + x];
    __syncthreads();
    for (int yy = y; yy < 32; yy += 8)
        d[(size_t)(c0 + yy) * 1024 + r0 + x] = __float2bfloat16(tile[x][yy]);
}

// ---------------------------------------------------------------- merged prep
// blocks [0,4096): pad_spatial; [4096,5120): cast node_enc; [5120,5152): spW1
// conversion; [5152,5168): sum b3 x4; [5168,5172): a1g (ahg W1 @ gfeat + b1)
struct PrepArgs {
    const float* spatial; bf16* spat_pad;
    const float* node_enc; bf16* enc_bf;
    const float* sp_W1; bf16* spW1t;
    const float* b3s0; const float* b3s1; const float* b3s2; const float* b3s3;
    float* b3d0; float* b3d1; float* b3d2; float* b3d3;
    const float* gf; const float* ahgW1; const float* ahgb1; float* a1g;
};
__global__ void prep_k(PrepArgs a)
{
    int bid = blockIdx.x, tid = threadIdx.x;
    if (bid < 4096) {
        int i = bid * 256 + tid;
        int k = i & 63, p = i >> 6;
        a.spat_pad[i] = __float2bfloat16(k < 36 ? a.spatial[p * 36 + k] : 0.f);
    } else if (bid < 5120) {
        int i = (bid - 4096) * 256 + tid;
        a.enc_bf[i] = __float2bfloat16(a.node_enc[i]);
    } else if (bid < 5152) {
        int i = (bid - 5120) * 256 + tid;
        int k = i & 63, n = i >> 6;
        a.spW1t[i] = __float2bfloat16(k < 36 ? a.sp_W1[k * 128 + n] : 0.f);
    } else if (bid < 5168) {
        int i = (bid - 5152) * 256 + tid;
        int pair = i >> 10, r = i & 1023;
        const float* b3 = (pair == 0) ? a.b3s0 : (pair == 1) ? a.b3s1 : (pair == 2) ? a.b3s2 : a.b3s3;
        float*       bd = (pair == 0) ? a.b3d0 : (pair == 1) ? a.b3d1 : (pair == 2) ? a.b3d2 : a.b3d3;
        float s = 0.f;
        #pragma unroll
        for (int c = 0; c < 16; ++c) s += b3[c * 1024 + r];
        bd[r] = s;
    } else {
        int cs = (bid - 5168) * 256 + tid;
        int c = cs >> 6, s = cs & 63;
        float acc = a.ahgb1[cs];
        for (int gg = 0; gg < 256; ++gg) acc += a.gf[gg] * a.ahgW1[((size_t)c * 256 + gg) * 64 + s];
        a.a1g[cs] = acc;
    }
}

// H = relu((Ah[p>>8] + Ao[p&255] + b1) * a2)
__global__ void hbuild(const float* __restrict__ Ah, int ah_ld,
                       const float* __restrict__ Ao, int ao_ld,
                       const float* __restrict__ b1, const bf16* __restrict__ a2,
                       bf16* __restrict__ H)
{
    size_t base = ((size_t)blockIdx.x * 256 + threadIdx.x) * 8;
    int cs = (int)(base & 1023);
    int p  = (int)(base >> 10);
    const float* ph = Ah + (size_t)(p >> 8) * ah_ld + cs;
    const float* po = Ao + (size_t)(p & 255) * ao_ld + cs;
    bf16x8 av = *(const bf16x8*)(a2 + base);
    bf16x8 o;
    #pragma unroll
    for (int j = 0; j < 8; ++j) {
        float a1 = ph[j] + po[j] + b1[cs + j];
        o[j] = (__bf16)fmaxf(a1 * (float)av[j], 0.f);
    }
    *(bf16x8*)(H + base) = o;
}

// ---------------------------------------------------------------- LN
__global__ void ln_k(const float* __restrict__ x, const float* __restrict__ msgraw,
                     const float* __restrict__ sb3,
                     const float* __restrict__ g, const float* __restrict__ bb,
                     bf16* __restrict__ out)
{
    int row = blockIdx.x, t = threadIdx.x;
    const float* xr = x + (size_t)row * 1024;
    const float* mr = msgraw + (size_t)row * 1024;
    float v[4]; float s = 0.f, ss = 0.f;
    #pragma unroll
    for (int j = 0; j < 4; ++j) {
        int i = t + j * 256;
        v[j] = xr[i] + fmaxf(mr[i] + sb3[i], 0.f);
        s += v[j]; ss += v[j] * v[j];
    }
    __shared__ float r1[256], r2[256];
    r1[t] = s; r2[t] = ss; __syncthreads();
    for (int k = 128; k > 0; k >>= 1) { if (t < k) { r1[t] += r1[t + k]; r2[t] += r2[t + k]; } __syncthreads(); }
    float mean = r1[0] * (1.f / 1024.f);
    float var  = r2[0] * (1.f / 1024.f) - mean * mean;
    float inv  = rsqrtf(var + 1e-5f);
    #pragma unroll
    for (int j = 0; j < 4; ++j) {
        int i = t + j * 256;
        out[(size_t)row * 1024 + i] = __float2bfloat16((v[j] - mean) * inv * g[i] + bb[i]);
    }
}

// ---------------------------------------------------------------- launch
extern "C" void kernel_launch(void* const* d_in, const int* in_sizes, int n_in,
                              void* d_out, int out_size, void* d_ws, size_t ws_size,
                              hipStream_t stream)
{
    const float* node_enc = (const float*)d_in[0];
    const float* spatial  = (const float*)d_in[1];
    const float* gfeat    = (const float*)d_in[2];
    const float* sp_W1 = (const float*)d_in[3];  const float* sp_b1 = (const float*)d_in[4];
    const float* sp_W2 = (const float*)d_in[5];  const float* sp_b2 = (const float*)d_in[6];
    const float* sp_W3 = (const float*)d_in[7];  const float* sp_b3 = (const float*)d_in[8];
    const float* ah_W1 = (const float*)d_in[9];  const float* ah_b1 = (const float*)d_in[10];
    const float* ah_W2 = (const float*)d_in[11]; const float* ah_b2 = (const float*)d_in[12];
    const float* ah_W3 = (const float*)d_in[13]; const float* ah_b3 = (const float*)d_in[14];
    const float* o2s_W1 = (const float*)d_in[15]; const float* o2s_b1 = (const float*)d_in[16];
    const float* o2s_W2 = (const float*)d_in[17]; const float* o2s_b2 = (const float*)d_in[18];
    const float* o2s_W3 = (const float*)d_in[19]; const float* o2s_b3 = (const float*)d_in[20];
    const float* s2o_W1 = (const float*)d_in[21]; const float* s2o_b1 = (const float*)d_in[22];
    const float* s2o_W2 = (const float*)d_in[23]; const float* s2o_b2 = (const float*)d_in[24];
    const float* s2o_W3 = (const float*)d_in[25]; const float* s2o_b3 = (const float*)d_in[26];
    const float* ahg_W1 = (const float*)d_in[27]; const float* ahg_b1 = (const float*)d_in[28];
    const float* ahg_W2 = (const float*)d_in[29]; const float* ahg_b2 = (const float*)d_in[30];
    const float* ahg_W3 = (const float*)d_in[31]; const float* ahg_b3 = (const float*)d_in[32];
    const float* adj_W = (const float*)d_in[33];
    const float* lnh_g = (const float*)d_in[35]; const float* lnh_b = (const float*)d_in[36];
    const float* lno_g = (const float*)d_in[37]; const float* lno_b = (const float*)d_in[38];

    char* w = (char*)d_ws;
    auto alloc = [&](size_t bytes) { char* p = w; w += (bytes + 255) & ~(size_t)255; return p; };
    bf16*  sp      = (bf16*)alloc((size_t)P_ * 1024 * 2);
    bf16*  a2_ah   = (bf16*)alloc((size_t)P_ * 1024 * 2);
    bf16*  Hbuf    = (bf16*)alloc((size_t)P_ * 1024 * 2);
    bf16*  a2_o2s  = (bf16*)alloc((size_t)P_ * 1024 * 2);
    bf16*  a2_s2o  = (bf16*)alloc((size_t)P_ * 1024 * 2);
    bf16*  H_ahg   = (bf16*)alloc((size_t)P_ * 1024 * 2);
    bf16*  spat_pad= (bf16*)alloc((size_t)P_ * 64 * 2);
    bf16*  spL1    = (bf16*)alloc((size_t)P_ * 128 * 2);
    bf16*  spL2    = (bf16*)alloc((size_t)P_ * 256 * 2);
    bf16*  enc_bf  = (bf16*)alloc(256 * 1024 * 2);
    bf16*  henc_bf = (bf16*)alloc(64 * 1024 * 2);
    bf16*  oenc_bf = (bf16*)alloc(256 * 1024 * 2);
    bf16*  HredH   = (bf16*)alloc(64 * 1024 * 2);
    bf16*  HredO   = (bf16*)alloc(256 * 1024 * 2);
    bf16*  spW1t   = (bf16*)alloc(128 * 64 * 2);
    bf16*  spW2t   = (bf16*)alloc(256 * 128 * 2);
    bf16*  spW3t   = (bf16*)alloc(1024 * 256 * 2);
    bf16*  W2cat   = (bf16*)alloc((size_t)4096 * 1024 * 2); // [ah; o2s; s2o; ahg]
    bf16*  W1cat3  = (bf16*)alloc((size_t)3072 * 1024 * 2); // [ahW1tB; o2sW1t; ahW1tT]
    bf16*  W1catF  = (bf16*)alloc((size_t)2048 * 1024 * 2); // [s2oW1t; ahW1tT]
    bf16*  ahW3t   = (bf16*)alloc(1024 * 1024 * 2);
    bf16*  o2sW3t  = (bf16*)alloc(1024 * 1024 * 2);
    bf16*  s2oW3t  = (bf16*)alloc(1024 * 1024 * 2);
    bf16*  ahgW3t  = (bf16*)alloc(1024 * 1024 * 2);
    // zero-init block (single memset: Aoa1x .. msgo are consecutive allocs)
    float* Aoa1x = (float*)alloc(256 * 3072 * 4);   // cols: Ao | a1o2s | Ah(rows<64)
    float* A1f   = (float*)alloc(64 * 2048 * 4);    // cols: a1s2o | Ah_f
    float* Ao_f  = (float*)alloc(256 * 1024 * 4);
    float* adjv  = (float*)alloc(P_ * 4);
    float* msgh  = (float*)alloc(64 * 1024 * 4);
    float* msgo  = (float*)alloc(256 * 1024 * 4);
    float* a1g   = (float*)alloc(1024 * 4);
    float* sb3_ah  = (float*)alloc(4096);
    float* sb3_o2s = (float*)alloc(4096);
    float* sb3_s2o = (float*)alloc(4096);
    float* sb3_ahg = (float*)alloc(4096);

    hipMemsetAsync(Aoa1x, 0, (size_t)((char*)a1g - (char*)Aoa1x), stream);

    // ---- batched weight conversions
    {
        T9 t;
        t.s[0] = ah_W1;                     t.d[0] = W1cat3 + (size_t)2048 * 1024; t.ss[0] = (size_t)2048 * 64; // ahT
        t.s[1] = ah_W1 + (size_t)1024 * 64; t.d[1] = W1cat3;                       t.ss[1] = (size_t)2048 * 64; // ahB
        t.s[2] = o2s_W1;                    t.d[2] = W1cat3 + (size_t)1024 * 1024; t.ss[2] = 65536;
        t.s[3] = s2o_W1;                    t.d[3] = W1catF;                       t.ss[3] = 65536;
        t.s[4] = ah_W1;                     t.d[4] = W1catF + (size_t)1024 * 1024; t.ss[4] = (size_t)2048 * 64; // ahT copy
        t.s[5] = ah_W2;                     t.d[5] = W2cat;                        t.ss[5] = 65536;
        t.s[6] = o2s_W2;                    t.d[6] = W2cat + (size_t)1024 * 1024;  t.ss[6] = 65536;
        t.s[7] = s2o_W2;                    t.d[7] = W2cat + (size_t)2048 * 1024;  t.ss[7] = 65536;
        t.s[8] = ahg_W2;                    t.d[8] = W2cat + (size_t)3072 * 1024;  t.ss[8] = 65536;
        transp64b<<<dim3(2, 32, 144), dim3(32, 8), 0, stream>>>(t);
    }
    {
        T4 t;
        t.s[0] = ah_W3;  t.d[0] = ahW3t;
        t.s[1] = o2s_W3; t.d[1] = o2sW3t;
        t.s[2] = s2o_W3; t.d[2] = s2oW3t;
        t.s[3] = ahg_W3; t.d[3] = ahgW3t;
        transp1024b<<<dim3(32, 32, 4), dim3(32, 8), 0, stream>>>(t);
    }
    dim3 tb(32, 8);
    transp<<<dim3(8, 4, 1),  tb, 0, stream>>>(sp_W2, spW2t, 128, 256, 0, 0);
    transp<<<dim3(32, 8, 1), tb, 0, stream>>>(sp_W3, spW3t, 256, 1024, 0, 0);
    {
        PrepArgs a;
        a.spatial = spatial; a.spat_pad = spat_pad;
        a.node_enc = node_enc; a.enc_bf = enc_bf;
        a.sp_W1 = sp_W1; a.spW1t = spW1t;
        a.b3s0 = ah_b3; a.b3s1 = o2s_b3; a.b3s2 = s2o_b3; a.b3s3 = ahg_b3;
        a.b3d0 = sb3_ah; a.b3d1 = sb3_o2s; a.b3d2 = sb3_s2o; a.b3d3 = sb3_ahg;
        a.gf = gfeat; a.ahgW1 = ahg_W1; a.ahgb1 = ahg_b1; a.a1g = a1g;
        prep_k<<<5172, 256, 0, stream>>>(a);
    }

    // ---- W1 split-K GEMM: enc @ [ahB | o2s | ahT] -> Aoa1x (256 x 3072)
    gemm_bt<2, false, false><<<dim3(2, 24, 16), 256, 0, stream>>>(
        mkargs(enc_bf, W1cat3, Aoa1x, nullptr, nullptr, 256, 3072, 1024, 3072, 64));

    // ---- sp MLP
    gemm_bt<1, true, true><<<dim3(128, 1), 256, 0, stream>>>(
        mkargs(spat_pad, spW1t, spL1, sp_b1, nullptr, P_, 128, 64, 128, 0));
    gemm_bt<1, true, true><<<dim3(128, 2), 256, 0, stream>>>(
        mkargs(spL1, spW2t, spL2, sp_b2, nullptr, P_, 256, 128, 256, 0));
    gemm_bt<1, true, true><<<dim3(128, 8), 256, 0, stream>>>(
        mkargs(spL2, spW3t, sp, sp_b3, nullptr, P_, 1024, 256, 1024, 0));

    // ---- merged W2 GEMM: N=4096 -> a2_ah+Hbuf | a2_o2s | a2_s2o | H_ahg
    {
        GArgs g = mkargs(sp, W2cat, a2_ah, nullptr, nullptr, P_, 4096, 1024, 1024, 0);
        g.dst1 = a2_o2s; g.dst2 = a2_s2o; g.dst3 = H_ahg; g.dstH = Hbuf;
        g.cb0 = ah_b2; g.cb1 = o2s_b2; g.cb2 = s2o_b2; g.cb3 = ahg_b2;
        g.a1gv = a1g; g.Ahp = Aoa1x + 2048; g.Aop = Aoa1x; g.b1p = ah_b1;
        gemm_bt<9, false, false><<<dim3(128, 32), 256, 0, stream>>>(g);
    }

    // ---- adj (softmaxes are fused into the reduce kernels)
    gemm_bt<6, false, false><<<dim3(128, 8), 256, 0, stream>>>(
        mkargs(Hbuf, ahW3t, adjv, sb3_ah, adj_W, P_, 1024, 1024, 1024, 0));

    // ---- msg_h = Hred_h @ o2sW3 -> h_enc'
    reduce_o2s<<<dim3(4, 64), 256, 0, stream>>>(a2_o2s, Aoa1x + 1024, o2s_b1, adjv, HredH);
    gemm_bt<2, false, false><<<dim3(1, 8, 16), 256, 0, stream>>>(
        mkargs(HredH, o2sW3t, msgh, nullptr, nullptr, 64, 1024, 1024, 1024, 64));
    ln_k<<<64, 256, 0, stream>>>(node_enc, msgh, sb3_o2s, lnh_g, lnh_b, henc_bf);

    // ---- {a1s2o | Ah_f}
    gemm_bt<2, false, false><<<dim3(1, 16, 16), 256, 0, stream>>>(
        mkargs(henc_bf, W1catF, A1f, nullptr, nullptr, 64, 2048, 1024, 2048, 64));

    // ---- msg_o = Hred_o @ s2oW3 -> o_enc'
    reduce_s2o<<<dim3(4, 256), 256, 0, stream>>>(a2_s2o, A1f, s2o_b1, adjv, HredO);
    gemm_bt<2, false, false><<<dim3(2, 8, 16), 256, 0, stream>>>(
        mkargs(HredO, s2oW3t, msgo, nullptr, nullptr, 256, 1024, 1024, 1024, 64));
    ln_k<<<256, 256, 0, stream>>>(node_enc, msgo, sb3_s2o, lno_g, lno_b, oenc_bf);

    // ---- Ao_f, final ah-head H
    gemm_bt<2, false, false><<<dim3(2, 8, 16), 256, 0, stream>>>(
        mkargs(oenc_bf, W1cat3, Ao_f, nullptr, nullptr, 256, 1024, 1024, 1024, 64));
    hbuild<<<8192, 256, 0, stream>>>(A1f + 1024, 2048, Ao_f, 1024, ah_b1, a2_ah, Hbuf);

    // ---- f_local (z=0) + f_glob (z=1) in one dispatch
    {
        GArgs g = mkargs(Hbuf, ahW3t, (float*)d_out, sb3_ah, nullptr, P_, 1024, 1024, 2048, 0);
        g.dst1 = (void*)H_ahg; g.dst2 = (void*)ahgW3t;
        g.dst3 = (void*)((float*)d_out + 1024); g.cb1 = sb3_ahg;
        gemm_bt<0, true, true><<<dim3(128, 8, 2), 256, 0, stream>>>(g);
    }

    (void)in_sizes; (void)n_in; (void)out_size; (void)ws_size;
}

// Round 10
// 750.190 us; speedup vs baseline: 1.1978x; 1.0333x over previous
//
#include <hip/hip_runtime.h>
#include <hip/hip_bf16.h>
#include <stdint.h>
#include <stddef.h>

using bf16 = __hip_bfloat16;
typedef __bf16 bf16x8 __attribute__((ext_vector_type(8)));
typedef float f32x4 __attribute__((ext_vector_type(4)));

#define P_  16384

// ---------------------------------------------------------------- async g->LDS
__device__ __forceinline__ void gload16(const void* g, void* l) {
    __builtin_amdgcn_global_load_lds((const __attribute__((address_space(1))) void*)g,
                                     (__attribute__((address_space(3))) void*)l, 16, 0, 0);
}

// ---------------------------------------------------------------- GEMM (B^T)
struct GArgs {
    const bf16* A; const bf16* B; void* C;
    const float* bias;    // column bias
    const float* aux1;    // adj_W (M6)
    int M, N, K, ldc, kchunk;
    // MODE 9 extras / MODE 0 dual (z=1) pointers:
    void* dst1; void* dst2; void* dst3; void* dstH;
    const float* cb0; const float* cb1; const float* cb2; const float* cb3;
    const float* a1gv; const float* Ahp; const float* Aop; const float* b1p;
};

// C[M,N] = A[M,K] @ B^T, B stored N x K row-major, both bf16.
// 128x128 tile, BK=64, XOR-swizzled LDS (slot = g ^ (row&7)), 4 waves 2x2,
// 4x4 frags of 16x16x32 MFMA.  (256,4): measured sweet spot — (256,5) spills
// (r5: VGPR 64->48, scratch 4x'd FETCH+WRITE, W2 200->554us).
// LINEAR blockIdx mapping is XCD-optimal here (r8 measured): XCD = lin%8 =
// blockIdx.x%8 pins each XCD's 16 A-panels (4MB = L2) across all y-iters;
// the chunked XCD swizzle broke that pinning (FETCH 203->532MB, W2 +50%).
// Do NOT add a block swizzle to this kernel.
// r10: MODE 2 uses g.kchunk (was hard-coded 64) — split-K depth z=4,
// kchunk=256 cuts per-output atomicAdd count 4x (~24M -> ~6M RMWs across
// the five split-K GEMMs) and amortizes staging over 4 K-iters/block.
// MODE 0: store fp32 (+bias/relu); grid.z==1 switches to {dst1,dst2,dst3,cb1}
// MODE 1: store bf16 (+bias/relu)
// MODE 2: split-K (kchunk=g.kchunk), atomicAdd fp32, grid.z = K/kchunk
// MODE 6: adj: atomicAdd(C[p], sum_c relu(acc+bias[c])*aux1[c])
// MODE 9: merged W2 quad: grp0 -> a2_ah bf16 + Hbuf fused; grp1 -> a2_o2s;
//         grp2 -> a2_s2o; grp3 -> H_ahg fused (a1g)
template<int MODE, bool RELU, bool BIAS>
__global__ __launch_bounds__(256, 4)
void gemm_bt(GArgs g)
{
    __shared__ __align__(16) bf16 As[128 * 64];
    __shared__ __align__(16) bf16 Bs[128 * 64];

    const int tid  = threadIdx.x;
    const int wave = tid >> 6;
    const int lane = tid & 63;
    const int tileM = blockIdx.x * 128;
    const int tileN = blockIdx.y * 128;
    const int wr = (wave >> 1) << 6;
    const int wc = (wave & 1) << 6;
    const int M = g.M, N = g.N, K = g.K;

    const bf16* Ap = g.A; const bf16* Bp = g.B;
    void* Cp = g.C; const float* biasp = g.bias;
    if (MODE == 0 && blockIdx.z == 1) {
        Ap = (const bf16*)g.dst1; Bp = (const bf16*)g.dst2;
        Cp = g.dst3; biasp = g.cb1;
    }

    f32x4 acc[4][4] = {};

    // staging: chunk c = wave*256 + j*64 + lane; row = c>>3; slot = c&7;
    // slot holds k-group g = slot ^ (row&7). For this thread:
    //   row&7 = lane>>3, slot = lane&7  ->  g = (lane&7)^(lane>>3)
    const int gk = (((lane & 7) ^ (lane >> 3)) << 3);   // k elem offset 0..56
    int arow[4], brow[4];
    #pragma unroll
    for (int j = 0; j < 4; ++j) {
        int r = wave * 32 + j * 8 + (lane >> 3);
        int gr = tileM + r; if (gr > M - 1) gr = M - 1; arow[j] = gr;
        int gn = tileN + r; if (gn > N - 1) gn = N - 1; brow[j] = gn;
    }
    const int m0 = wr + (lane & 15);
    const int n0 = wc + (lane & 15);
    const int q  = lane >> 4;

    int kbeg = 0, kend = K;
    if constexpr (MODE == 2) { kbeg = blockIdx.z * g.kchunk; kend = kbeg + g.kchunk; }

    for (int k0 = kbeg; k0 < kend; k0 += 64) {
        #pragma unroll
        for (int j = 0; j < 4; ++j) {
            int c = wave * 256 + j * 64 + lane;
            gload16(Ap + (size_t)arow[j] * K + k0 + gk, (void*)(As + c * 8));
            gload16(Bp + (size_t)brow[j] * K + k0 + gk, (void*)(Bs + c * 8));
        }
        __syncthreads();
        #pragma unroll
        for (int kk = 0; kk < 2; ++kk) {
            // fragment k-group g = kk*4 + q; LDS slot = g ^ (row&7); row&7 = lane&7
            const int gs = ((kk << 2) + q) ^ (lane & 7);
            bf16x8 af[4], bfv[4];
            #pragma unroll
            for (int i = 0; i < 4; ++i) {
                af[i]  = *(const bf16x8*)(As + (m0 + i * 16) * 64 + gs * 8);
                bfv[i] = *(const bf16x8*)(Bs + (n0 + i * 16) * 64 + gs * 8);
            }
            #pragma unroll
            for (int i = 0; i < 4; ++i)
                #pragma unroll
                for (int j = 0; j < 4; ++j)
                    acc[i][j] = __builtin_amdgcn_mfma_f32_16x16x32_bf16(af[i], bfv[j], acc[i][j], 0, 0, 0);
        }
        __syncthreads();
    }

    const int rbase = tileM + wr + ((lane >> 4) << 2);
    const int cbase = tileN + wc + (lane & 15);

    if constexpr (MODE == 0 || MODE == 1) {
        #pragma unroll
        for (int i = 0; i < 4; ++i)
            #pragma unroll
            for (int j = 0; j < 4; ++j)
                #pragma unroll
                for (int r = 0; r < 4; ++r) {
                    int grow = rbase + i * 16 + r;
                    if (grow >= M) continue;
                    int gcol = cbase + j * 16;
                    float v = acc[i][j][r];
                    if (BIAS) v += biasp[gcol];
                    if (RELU) v = fmaxf(v, 0.f);
                    if (MODE == 1) ((bf16*)Cp)[(size_t)grow * g.ldc + gcol] = __float2bfloat16(v);
                    else           ((float*)Cp)[(size_t)grow * g.ldc + gcol] = v;
                }
    } else if constexpr (MODE == 2) {
        #pragma unroll
        for (int i = 0; i < 4; ++i)
            #pragma unroll
            for (int j = 0; j < 4; ++j)
                #pragma unroll
                for (int r = 0; r < 4; ++r) {
                    int grow = rbase + i * 16 + r;
                    if (grow >= M) continue;
                    atomicAdd((float*)Cp + (size_t)grow * g.ldc + cbase + j * 16, acc[i][j][r]);
                }
    } else if constexpr (MODE == 6) {
        #pragma unroll
        for (int i = 0; i < 4; ++i)
            #pragma unroll
            for (int r = 0; r < 4; ++r) {
                float s = 0.f;
                #pragma unroll
                for (int j = 0; j < 4; ++j) {
                    int gcol = cbase + j * 16;
                    s += fmaxf(acc[i][j][r] + biasp[gcol], 0.f) * g.aux1[gcol];
                }
                s += __shfl_xor(s, 1); s += __shfl_xor(s, 2);
                s += __shfl_xor(s, 4); s += __shfl_xor(s, 8);
                if ((lane & 15) == 0)
                    atomicAdd((float*)Cp + rbase + i * 16 + r, s);
            }
    } else if constexpr (MODE == 9) {
        int grp = tileN >> 10;
        int lcb = (tileN & 1023) + wc + (lane & 15);
        #pragma unroll
        for (int i = 0; i < 4; ++i)
            #pragma unroll
            for (int j = 0; j < 4; ++j)
                #pragma unroll
                for (int r = 0; r < 4; ++r) {
                    int p    = rbase + i * 16 + r;
                    int lcol = lcb + j * 16;
                    float accv = acc[i][j][r];
                    if (grp == 0) {
                        bf16 a2b = __float2bfloat16(accv + g.cb0[lcol]);
                        ((bf16*)Cp)[(size_t)p * 1024 + lcol] = a2b;
                        float a1 = g.Ahp[((size_t)(p >> 8)) * 3072 + lcol]
                                 + g.Aop[((size_t)(p & 255)) * 3072 + lcol] + g.b1p[lcol];
                        ((bf16*)g.dstH)[(size_t)p * 1024 + lcol] =
                            __float2bfloat16(fmaxf(a1 * (float)a2b, 0.f));
                    } else if (grp == 1) {
                        ((bf16*)g.dst1)[(size_t)p * 1024 + lcol] =
                            __float2bfloat16(accv + g.cb1[lcol]);
                    } else if (grp == 2) {
                        ((bf16*)g.dst2)[(size_t)p * 1024 + lcol] =
                            __float2bfloat16(accv + g.cb2[lcol]);
                    } else {
                        float a2v = accv + g.cb3[lcol];
                        ((bf16*)g.dst3)[(size_t)p * 1024 + lcol] =
                            __float2bfloat16(fmaxf(g.a1gv[lcol] * a2v, 0.f));
                    }
                }
    }
}

static GArgs mkargs(const bf16* A, const bf16* B, void* C, const float* bias,
                    const float* aux1, int M, int N, int K, int ldc, int kchunk)
{
    GArgs g{};
    g.A = A; g.B = B; g.C = C; g.bias = bias; g.aux1 = aux1;
    g.M = M; g.N = N; g.K = K; g.ldc = ldc; g.kchunk = kchunk;
    return g;
}

// ---------------------------------------------------------------- reductions over H
// Fused row-softmax (over n) + HredH[h,c] = sum_n sh[h,n] *
//   relu((a1[n,c]+b1[c]) * a2[(h*256+n),c]), a1 ld=3072.
__global__ void reduce_o2s(const bf16* __restrict__ a2, const float* __restrict__ a1,
                           const float* __restrict__ b1, const float* __restrict__ adj,
                           bf16* __restrict__ out)
{
    int h = blockIdx.y, cq = blockIdx.x;
    int tid = threadIdx.x;
    int ng = tid >> 5, ct = tid & 31;
    int c = cq * 256 + ct * 8;

    __shared__ float sm[256];
    __shared__ float r1[256];
    {
        float v = adj[h * 256 + tid];
        r1[tid] = v; __syncthreads();
        for (int s = 128; s > 0; s >>= 1) { if (tid < s) r1[tid] = fmaxf(r1[tid], r1[tid + s]); __syncthreads(); }
        float m = r1[0]; __syncthreads();
        float e = expf(v - m);
        r1[tid] = e; __syncthreads();
        for (int s = 128; s > 0; s >>= 1) { if (tid < s) r1[tid] += r1[tid + s]; __syncthreads(); }
        sm[tid] = e / r1[0];
        __syncthreads();
    }

    float b1v[8], accv[8] = {};
    #pragma unroll
    for (int j = 0; j < 8; ++j) b1v[j] = b1[c + j];
    for (int n = ng; n < 256; n += 8) {
        float w = sm[n];
        bf16x8 a2v = *(const bf16x8*)(a2 + ((size_t)(h * 256 + n) << 10) + c);
        const float* a1p = a1 + (size_t)n * 3072 + c;
        #pragma unroll
        for (int j = 0; j < 8; ++j)
            accv[j] += w * fmaxf((a1p[j] + b1v[j]) * (float)a2v[j], 0.f);
    }
    __shared__ float red[8][264];
    #pragma unroll
    for (int j = 0; j < 8; ++j) red[ng][ct * 8 + j] = accv[j];
    __syncthreads();
    for (int s = 4; s > 0; s >>= 1) {
        if (ng < s)
            #pragma unroll
            for (int j = 0; j < 8; ++j) red[ng][ct * 8 + j] += red[ng + s][ct * 8 + j];
        __syncthreads();
    }
    if (ng == 0) {
        bf16x8 o;
        #pragma unroll
        for (int j = 0; j < 8; ++j) o[j] = (__bf16)red[0][ct * 8 + j];
        *(bf16x8*)(out + (size_t)h * 1024 + c) = o;
    }
}

// Fused col-softmax (over h) + HredO[n,c] = sum_h so[n,h] *
//   relu((a1[h,c]+b1[c]) * a2[(h*256+n),c]), a1 ld=2048.
__global__ void reduce_s2o(const bf16* __restrict__ a2, const float* __restrict__ a1,
                           const float* __restrict__ b1, const float* __restrict__ adj,
                           bf16* __restrict__ out)
{
    int n = blockIdx.y, cq = blockIdx.x;
    int tid = threadIdx.x;
    int hg = tid >> 5, ct = tid & 31;
    int c = cq * 256 + ct * 8;

    __shared__ float sm[64];
    if (tid < 64) {
        float v = adj[tid * 256 + n];
        float m = v;
        #pragma unroll
        for (int off = 32; off; off >>= 1) m = fmaxf(m, __shfl_xor(m, off));
        float e = expf(v - m);
        float s = e;
        #pragma unroll
        for (int off = 32; off; off >>= 1) s += __shfl_xor(s, off);
        sm[tid] = e / s;
    }
    __syncthreads();

    float b1v[8], accv[8] = {};
    #pragma unroll
    for (int j = 0; j < 8; ++j) b1v[j] = b1[c + j];
    #pragma unroll
    for (int hh = 0; hh < 8; ++hh) {
        int h = hg + hh * 8;
        float w = sm[h];
        bf16x8 a2v = *(const bf16x8*)(a2 + ((size_t)(h * 256 + n) << 10) + c);
        const float* a1p = a1 + (size_t)h * 2048 + c;
        #pragma unroll
        for (int j = 0; j < 8; ++j)
            accv[j] += w * fmaxf((a1p[j] + b1v[j]) * (float)a2v[j], 0.f);
    }
    __shared__ float red[8][264];
    #pragma unroll
    for (int j = 0; j < 8; ++j) red[hg][ct * 8 + j] = accv[j];
    __syncthreads();
    for (int s = 4; s > 0; s >>= 1) {
        if (hg < s)
            #pragma unroll
            for (int j = 0; j < 8; ++j) red[hg][ct * 8 + j] += red[hg + s][ct * 8 + j];
        __syncthreads();
    }
    if (hg == 0) {
        bf16x8 o;
        #pragma unroll
        for (int j = 0; j < 8; ++j) o[j] = (__bf16)red[0][ct * 8 + j];
        *(bf16x8*)(out + (size_t)n * 1024 + c) = o;
    }
}

// ---------------------------------------------------------------- transposes
__global__ void transp(const float* __restrict__ src, bf16* __restrict__ dst,
                       int rows, int cols, size_t sstride, size_t dstride)
{
    const float* s = src + blockIdx.z * sstride;
    bf16*        d = dst + blockIdx.z * dstride;
    __shared__ float tile[32][33];
    int c0 = blockIdx.x * 32, r0 = blockIdx.y * 32;
    int x = threadIdx.x, y = threadIdx.y;   // (32, 8)
    for (int yy = y; yy < 32; yy += 8) {
        int r = r0 + yy, c = c0 + x;
        tile[yy][x] = (r < rows && c < cols) ? s[(size_t)r * cols + c] : 0.f;
    }
    __syncthreads();
    for (int yy = y; yy < 32; yy += 8) {
        int c = c0 + yy, r = r0 + x;
        if (c < cols && r < rows) d[(size_t)c * rows + r] = __float2bfloat16(tile[x][yy]);
    }
}

struct T9 { const float* s[9]; bf16* d[9]; size_t ss[9]; };
// 9 weights, each 16 z-slices of 1024x64 -> 64x1024; grid (2, 32, 144)
__global__ void transp64b(T9 t)
{
    int pair = blockIdx.z >> 4, slice = blockIdx.z & 15;
    const float* s = t.s[pair] + slice * t.ss[pair];
    bf16*        d = t.d[pair] + slice * 65536;
    __shared__ float tile[32][33];
    int c0 = blockIdx.x * 32, r0 = blockIdx.y * 32;
    int x = threadIdx.x, y = threadIdx.y;
    for (int yy = y; yy < 32; yy += 8)
        tile[yy][x] = s[(size_t)(r0 + yy) * 64 + c0 + x];
    __syncthreads();
    for (int yy = y; yy < 32; yy += 8)
        d[(size_t)(c0 + yy) * 1024 + r0 + x] = __float2bfloat16(tile[x][yy]);
}

struct T4 { const float* s[4]; bf16* d[4]; };
__global__ void transp1024b(T4 t)
{
    const float* s = t.s[blockIdx.z];
    bf16*        d = t.d[blockIdx.z];
    __shared__ float tile[32][33];
    int c0 = blockIdx.x * 32, r0 = blockIdx.y * 32;
    int x = threadIdx.x, y = threadIdx.y;
    for (int yy = y; yy < 32; yy += 8)
        tile[yy][x] = s[(size_t)(r0 + yy) * 1024 + c0 + x];
    __syncthreads();
    for (int yy = y; yy < 32; yy += 8)
        d[(size_t)(c0 + yy) * 1024 + r0 + x] = __float2bfloat16(tile[x][yy]);
}

// ---------------------------------------------------------------- merged prep
// blocks [0,4096): pad_spatial; [4096,5120): cast node_enc; [5120,5152): spW1
// conversion; [5152,5168): sum b3 x4; [5168,5172): a1g (ahg W1 @ gfeat + b1)
struct PrepArgs {
    const float* spatial; bf16* spat_pad;
    const float* node_enc; bf16* enc_bf;
    const float* sp_W1; bf16* spW1t;
    const float* b3s0; const float* b3s1; const float* b3s2; const float* b3s3;
    float* b3d0; float* b3d1; float* b3d2; float* b3d3;
    const float* gf; const float* ahgW1; const float* ahgb1; float* a1g;
};
__global__ void prep_k(PrepArgs a)
{
    int bid = blockIdx.x, tid = threadIdx.x;
    if (bid < 4096) {
        int i = bid * 256 + tid;
        int k = i & 63, p = i >> 6;
        a.spat_pad[i] = __float2bfloat16(k < 36 ? a.spatial[p * 36 + k] : 0.f);
    } else if (bid < 5120) {
        int i = (bid - 4096) * 256 + tid;
        a.enc_bf[i] = __float2bfloat16(a.node_enc[i]);
    } else if (bid < 5152) {
        int i = (bid - 5120) * 256 + tid;
        int k = i & 63, n = i >> 6;
        a.spW1t[i] = __float2bfloat16(k < 36 ? a.sp_W1[k * 128 + n] : 0.f);
    } else if (bid < 5168) {
        int i = (bid - 5152) * 256 + tid;
        int pair = i >> 10, r = i & 1023;
        const float* b3 = (pair == 0) ? a.b3s0 : (pair == 1) ? a.b3s1 : (pair == 2) ? a.b3s2 : a.b3s3;
        float*       bd = (pair == 0) ? a.b3d0 : (pair == 1) ? a.b3d1 : (pair == 2) ? a.b3d2 : a.b3d3;
        float s = 0.f;
        #pragma unroll
        for (int c = 0; c < 16; ++c) s += b3[c * 1024 + r];
        bd[r] = s;
    } else {
        int cs = (bid - 5168) * 256 + tid;
        int c = cs >> 6, s = cs & 63;
        float acc = a.ahgb1[cs];
        for (int gg = 0; gg < 256; ++gg) acc += a.gf[gg] * a.ahgW1[((size_t)c * 256 + gg) * 64 + s];
        a.a1g[cs] = acc;
    }
}

// H = relu((Ah[p>>8] + Ao[p&255] + b1) * a2)
__global__ void hbuild(const float* __restrict__ Ah, int ah_ld,
                       const float* __restrict__ Ao, int ao_ld,
                       const float* __restrict__ b1, const bf16* __restrict__ a2,
                       bf16* __restrict__ H)
{
    size_t base = ((size_t)blockIdx.x * 256 + threadIdx.x) * 8;
    int cs = (int)(base & 1023);
    int p  = (int)(base >> 10);
    const float* ph = Ah + (size_t)(p >> 8) * ah_ld + cs;
    const float* po = Ao + (size_t)(p & 255) * ao_ld + cs;
    bf16x8 av = *(const bf16x8*)(a2 + base);
    bf16x8 o;
    #pragma unroll
    for (int j = 0; j < 8; ++j) {
        float a1 = ph[j] + po[j] + b1[cs + j];
        o[j] = (__bf16)fmaxf(a1 * (float)av[j], 0.f);
    }
    *(bf16x8*)(H + base) = o;
}

// ---------------------------------------------------------------- LN
__global__ void ln_k(const float* __restrict__ x, const float* __restrict__ msgraw,
                     const float* __restrict__ sb3,
                     const float* __restrict__ g, const float* __restrict__ bb,
                     bf16* __restrict__ out)
{
    int row = blockIdx.x, t = threadIdx.x;
    const float* xr = x + (size_t)row * 1024;
    const float* mr = msgraw + (size_t)row * 1024;
    float v[4]; float s = 0.f, ss = 0.f;
    #pragma unroll
    for (int j = 0; j < 4; ++j) {
        int i = t + j * 256;
        v[j] = xr[i] + fmaxf(mr[i] + sb3[i], 0.f);
        s += v[j]; ss += v[j] * v[j];
    }
    __shared__ float r1[256], r2[256];
    r1[t] = s; r2[t] = ss; __syncthreads();
    for (int k = 128; k > 0; k >>= 1) { if (t < k) { r1[t] += r1[t + k]; r2[t] += r2[t + k]; } __syncthreads(); }
    float mean = r1[0] * (1.f / 1024.f);
    float var  = r2[0] * (1.f / 1024.f) - mean * mean;
    float inv  = rsqrtf(var + 1e-5f);
    #pragma unroll
    for (int j = 0; j < 4; ++j) {
        int i = t + j * 256;
        out[(size_t)row * 1024 + i] = __float2bfloat16((v[j] - mean) * inv * g[i] + bb[i]);
    }
}

// ---------------------------------------------------------------- launch
extern "C" void kernel_launch(void* const* d_in, const int* in_sizes, int n_in,
                              void* d_out, int out_size, void* d_ws, size_t ws_size,
                              hipStream_t stream)
{
    const float* node_enc = (const float*)d_in[0];
    const float* spatial  = (const float*)d_in[1];
    const float* gfeat    = (const float*)d_in[2];
    const float* sp_W1 = (const float*)d_in[3];  const float* sp_b1 = (const float*)d_in[4];
    const float* sp_W2 = (const float*)d_in[5];  const float* sp_b2 = (const float*)d_in[6];
    const float* sp_W3 = (const float*)d_in[7];  const float* sp_b3 = (const float*)d_in[8];
    const float* ah_W1 = (const float*)d_in[9];  const float* ah_b1 = (const float*)d_in[10];
    const float* ah_W2 = (const float*)d_in[11]; const float* ah_b2 = (const float*)d_in[12];
    const float* ah_W3 = (const float*)d_in[13]; const float* ah_b3 = (const float*)d_in[14];
    const float* o2s_W1 = (const float*)d_in[15]; const float* o2s_b1 = (const float*)d_in[16];
    const float* o2s_W2 = (const float*)d_in[17]; const float* o2s_b2 = (const float*)d_in[18];
    const float* o2s_W3 = (const float*)d_in[19]; const float* o2s_b3 = (const float*)d_in[20];
    const float* s2o_W1 = (const float*)d_in[21]; const float* s2o_b1 = (const float*)d_in[22];
    const float* s2o_W2 = (const float*)d_in[23]; const float* s2o_b2 = (const float*)d_in[24];
    const float* s2o_W3 = (const float*)d_in[25]; const float* s2o_b3 = (const float*)d_in[26];
    const float* ahg_W1 = (const float*)d_in[27]; const float* ahg_b1 = (const float*)d_in[28];
    const float* ahg_W2 = (const float*)d_in[29]; const float* ahg_b2 = (const float*)d_in[30];
    const float* ahg_W3 = (const float*)d_in[31]; const float* ahg_b3 = (const float*)d_in[32];
    const float* adj_W = (const float*)d_in[33];
    const float* lnh_g = (const float*)d_in[35]; const float* lnh_b = (const float*)d_in[36];
    const float* lno_g = (const float*)d_in[37]; const float* lno_b = (const float*)d_in[38];

    char* w = (char*)d_ws;
    auto alloc = [&](size_t bytes) { char* p = w; w += (bytes + 255) & ~(size_t)255; return p; };
    bf16*  sp      = (bf16*)alloc((size_t)P_ * 1024 * 2);
    bf16*  a2_ah   = (bf16*)alloc((size_t)P_ * 1024 * 2);
    bf16*  Hbuf    = (bf16*)alloc((size_t)P_ * 1024 * 2);
    bf16*  a2_o2s  = (bf16*)alloc((size_t)P_ * 1024 * 2);
    bf16*  a2_s2o  = (bf16*)alloc((size_t)P_ * 1024 * 2);
    bf16*  H_ahg   = (bf16*)alloc((size_t)P_ * 1024 * 2);
    bf16*  spat_pad= (bf16*)alloc((size_t)P_ * 64 * 2);
    bf16*  spL1    = (bf16*)alloc((size_t)P_ * 128 * 2);
    bf16*  spL2    = (bf16*)alloc((size_t)P_ * 256 * 2);
    bf16*  enc_bf  = (bf16*)alloc(256 * 1024 * 2);
    bf16*  henc_bf = (bf16*)alloc(64 * 1024 * 2);
    bf16*  oenc_bf = (bf16*)alloc(256 * 1024 * 2);
    bf16*  HredH   = (bf16*)alloc(64 * 1024 * 2);
    bf16*  HredO   = (bf16*)alloc(256 * 1024 * 2);
    bf16*  spW1t   = (bf16*)alloc(128 * 64 * 2);
    bf16*  spW2t   = (bf16*)alloc(256 * 128 * 2);
    bf16*  spW3t   = (bf16*)alloc(1024 * 256 * 2);
    bf16*  W2cat   = (bf16*)alloc((size_t)4096 * 1024 * 2); // [ah; o2s; s2o; ahg]
    bf16*  W1cat3  = (bf16*)alloc((size_t)3072 * 1024 * 2); // [ahW1tB; o2sW1t; ahW1tT]
    bf16*  W1catF  = (bf16*)alloc((size_t)2048 * 1024 * 2); // [s2oW1t; ahW1tT]
    bf16*  ahW3t   = (bf16*)alloc(1024 * 1024 * 2);
    bf16*  o2sW3t  = (bf16*)alloc(1024 * 1024 * 2);
    bf16*  s2oW3t  = (bf16*)alloc(1024 * 1024 * 2);
    bf16*  ahgW3t  = (bf16*)alloc(1024 * 1024 * 2);
    // zero-init block (single memset: Aoa1x .. msgo are consecutive allocs)
    float* Aoa1x = (float*)alloc(256 * 3072 * 4);   // cols: Ao | a1o2s | Ah(rows<64)
    float* A1f   = (float*)alloc(64 * 2048 * 4);    // cols: a1s2o | Ah_f
    float* Ao_f  = (float*)alloc(256 * 1024 * 4);
    float* adjv  = (float*)alloc(P_ * 4);
    float* msgh  = (float*)alloc(64 * 1024 * 4);
    float* msgo  = (float*)alloc(256 * 1024 * 4);
    float* a1g   = (float*)alloc(1024 * 4);
    float* sb3_ah  = (float*)alloc(4096);
    float* sb3_o2s = (float*)alloc(4096);
    float* sb3_s2o = (float*)alloc(4096);
    float* sb3_ahg = (float*)alloc(4096);

    hipMemsetAsync(Aoa1x, 0, (size_t)((char*)a1g - (char*)Aoa1x), stream);

    // ---- batched weight conversions
    {
        T9 t;
        t.s[0] = ah_W1;                     t.d[0] = W1cat3 + (size_t)2048 * 1024; t.ss[0] = (size_t)2048 * 64; // ahT
        t.s[1] = ah_W1 + (size_t)1024 * 64; t.d[1] = W1cat3;                       t.ss[1] = (size_t)2048 * 64; // ahB
        t.s[2] = o2s_W1;                    t.d[2] = W1cat3 + (size_t)1024 * 1024; t.ss[2] = 65536;
        t.s[3] = s2o_W1;                    t.d[3] = W1catF;                       t.ss[3] = 65536;
        t.s[4] = ah_W1;                     t.d[4] = W1catF + (size_t)1024 * 1024; t.ss[4] = (size_t)2048 * 64; // ahT copy
        t.s[5] = ah_W2;                     t.d[5] = W2cat;                        t.ss[5] = 65536;
        t.s[6] = o2s_W2;                    t.d[6] = W2cat + (size_t)1024 * 1024;  t.ss[6] = 65536;
        t.s[7] = s2o_W2;                    t.d[7] = W2cat + (size_t)2048 * 1024;  t.ss[7] = 65536;
        t.s[8] = ahg_W2;                    t.d[8] = W2cat + (size_t)3072 * 1024;  t.ss[8] = 65536;
        transp64b<<<dim3(2, 32, 144), dim3(32, 8), 0, stream>>>(t);
    }
    {
        T4 t;
        t.s[0] = ah_W3;  t.d[0] = ahW3t;
        t.s[1] = o2s_W3; t.d[1] = o2sW3t;
        t.s[2] = s2o_W3; t.d[2] = s2oW3t;
        t.s[3] = ahg_W3; t.d[3] = ahgW3t;
        transp1024b<<<dim3(32, 32, 4), dim3(32, 8), 0, stream>>>(t);
    }
    dim3 tb(32, 8);
    transp<<<dim3(8, 4, 1),  tb, 0, stream>>>(sp_W2, spW2t, 128, 256, 0, 0);
    transp<<<dim3(32, 8, 1), tb, 0, stream>>>(sp_W3, spW3t, 256, 1024, 0, 0);
    {
        PrepArgs a;
        a.spatial = spatial; a.spat_pad = spat_pad;
        a.node_enc = node_enc; a.enc_bf = enc_bf;
        a.sp_W1 = sp_W1; a.spW1t = spW1t;
        a.b3s0 = ah_b3; a.b3s1 = o2s_b3; a.b3s2 = s2o_b3; a.b3s3 = ahg_b3;
        a.b3d0 = sb3_ah; a.b3d1 = sb3_o2s; a.b3d2 = sb3_s2o; a.b3d3 = sb3_ahg;
        a.gf = gfeat; a.ahgW1 = ahg_W1; a.ahgb1 = ahg_b1; a.a1g = a1g;
        prep_k<<<5172, 256, 0, stream>>>(a);
    }

    // ---- W1 split-K GEMM: enc @ [ahB | o2s | ahT] -> Aoa1x (256 x 3072)
    gemm_bt<2, false, false><<<dim3(2, 24, 4), 256, 0, stream>>>(
        mkargs(enc_bf, W1cat3, Aoa1x, nullptr, nullptr, 256, 3072, 1024, 3072, 256));

    // ---- sp MLP
    gemm_bt<1, true, true><<<dim3(128, 1), 256, 0, stream>>>(
        mkargs(spat_pad, spW1t, spL1, sp_b1, nullptr, P_, 128, 64, 128, 0));
    gemm_bt<1, true, true><<<dim3(128, 2), 256, 0, stream>>>(
        mkargs(spL1, spW2t, spL2, sp_b2, nullptr, P_, 256, 128, 256, 0));
    gemm_bt<1, true, true><<<dim3(128, 8), 256, 0, stream>>>(
        mkargs(spL2, spW3t, sp, sp_b3, nullptr, P_, 1024, 256, 1024, 0));

    // ---- merged W2 GEMM: N=4096 -> a2_ah+Hbuf | a2_o2s | a2_s2o | H_ahg
    {
        GArgs g = mkargs(sp, W2cat, a2_ah, nullptr, nullptr, P_, 4096, 1024, 1024, 0);
        g.dst1 = a2_o2s; g.dst2 = a2_s2o; g.dst3 = H_ahg; g.dstH = Hbuf;
        g.cb0 = ah_b2; g.cb1 = o2s_b2; g.cb2 = s2o_b2; g.cb3 = ahg_b2;
        g.a1gv = a1g; g.Ahp = Aoa1x + 2048; g.Aop = Aoa1x; g.b1p = ah_b1;
        gemm_bt<9, false, false><<<dim3(128, 32), 256, 0, stream>>>(g);
    }

    // ---- adj (softmaxes are fused into the reduce kernels)
    gemm_bt<6, false, false><<<dim3(128, 8), 256, 0, stream>>>(
        mkargs(Hbuf, ahW3t, adjv, sb3_ah, adj_W, P_, 1024, 1024, 1024, 0));

    // ---- msg_h = Hred_h @ o2sW3 -> h_enc'
    reduce_o2s<<<dim3(4, 64), 256, 0, stream>>>(a2_o2s, Aoa1x + 1024, o2s_b1, adjv, HredH);
    gemm_bt<2, false, false><<<dim3(1, 8, 4), 256, 0, stream>>>(
        mkargs(HredH, o2sW3t, msgh, nullptr, nullptr, 64, 1024, 1024, 1024, 256));
    ln_k<<<64, 256, 0, stream>>>(node_enc, msgh, sb3_o2s, lnh_g, lnh_b, henc_bf);

    // ---- {a1s2o | Ah_f}
    gemm_bt<2, false, false><<<dim3(1, 16, 4), 256, 0, stream>>>(
        mkargs(henc_bf, W1catF, A1f, nullptr, nullptr, 64, 2048, 1024, 2048, 256));

    // ---- msg_o = Hred_o @ s2oW3 -> o_enc'
    reduce_s2o<<<dim3(4, 256), 256, 0, stream>>>(a2_s2o, A1f, s2o_b1, adjv, HredO);
    gemm_bt<2, false, false><<<dim3(2, 8, 4), 256, 0, stream>>>(
        mkargs(HredO, s2oW3t, msgo, nullptr, nullptr, 256, 1024, 1024, 1024, 256));
    ln_k<<<256, 256, 0, stream>>>(node_enc, msgo, sb3_s2o, lno_g, lno_b, oenc_bf);

    // ---- Ao_f, final ah-head H
    gemm_bt<2, false, false><<<dim3(2, 8, 4), 256, 0, stream>>>(
        mkargs(oenc_bf, W1cat3, Ao_f, nullptr, nullptr, 256, 1024, 1024, 1024, 256));
    hbuild<<<8192, 256, 0, stream>>>(A1f + 1024, 2048, Ao_f, 1024, ah_b1, a2_ah, Hbuf);

    // ---- f_local (z=0) + f_glob (z=1) in one dispatch
    {
        GArgs g = mkargs(Hbuf, ahW3t, (float*)d_out, sb3_ah, nullptr, P_, 1024, 1024, 2048, 0);
        g.dst1 = (void*)H_ahg; g.dst2 = (void*)ahgW3t;
        g.dst3 = (void*)((float*)d_out + 1024); g.cb1 = sb3_ahg;
        gemm_bt<0, true, true><<<dim3(128, 8, 2), 256, 0, stream>>>(g);
    }

    (void)in_sizes; (void)n_in; (void)out_size; (void)ws_size;
}